// Round 20
// baseline (255.771 us; speedup 1.0000x reference)
//
#include <hip/hip_runtime.h>

typedef __attribute__((ext_vector_type(4))) float f4;
typedef __attribute__((ext_vector_type(8))) short bfx8;
typedef __attribute__((ext_vector_type(4))) float f32x4;
typedef __attribute__((ext_vector_type(4))) unsigned int u32x4;
typedef __attribute__((ext_vector_type(4))) unsigned short u16x4;
typedef __attribute__((ext_vector_type(8))) unsigned short u16x8;
typedef unsigned short ushort_t;

#define DM 768
#define DINNER 1536
#define NH 24
#define XBCW 1664
#define DINPROJ 3224
#define NPAD1 3328
#define NCHUNK 64
#define BROWS 8192
#define PADB 72  // bf16 LDS row stride for 64-wide tiles

__device__ inline ushort_t f2bf(float f) {
    unsigned u = __builtin_bit_cast(unsigned, f);
    unsigned r = (u + 0x7FFF + ((u >> 16) & 1)) >> 16;
    return (ushort_t)r;
}
__device__ inline float bf2f(ushort_t u) {
    return __builtin_bit_cast(float, (unsigned)u << 16);
}
// direct global->LDS 16B staging. dst wave-uniform; HW adds lane*16.
__device__ inline void gl16(const void* g, void* l) {
    __builtin_amdgcn_global_load_lds((const __attribute__((address_space(1))) void*)g,
                                     (__attribute__((address_space(3))) void*)l, 16, 0, 0);
}

__global__ __launch_bounds__(256) void fill_kernel(float* out, int n, float v) {
    int i = blockIdx.x * 256 + threadIdx.x;
    if (i < n) out[i] = v;
}

// ---- all three f32->bf16 input conversions in one launch ----
// seg0: u [8192x768]; seg1: W_in pad [3224x768 -> 3328x768]; seg2: W_out [768x1536]
__global__ __launch_bounds__(256) void cvt_all(const float* __restrict__ u,
                                               const float* __restrict__ W_in,
                                               const float* __restrict__ W_out,
                                               ushort_t* __restrict__ ubf,
                                               ushort_t* __restrict__ winbf,
                                               ushort_t* __restrict__ woutbf) {
    const long NU = (long)BROWS * DM / 4;
    const long NW = (long)NPAD1 * 192;
    const long NO = (long)DM * DINNER / 4;
    long q = (long)blockIdx.x * 256 + threadIdx.x;
    if (q < NU) {
        f4 v = *(const f4*)&u[q * 4];
        u16x4 o;
        o[0] = f2bf(v[0]); o[1] = f2bf(v[1]); o[2] = f2bf(v[2]); o[3] = f2bf(v[3]);
        *(u16x4*)&ubf[q * 4] = o;
    } else if (q < NU + NW) {
        long p = q - NU;
        int row = (int)(p / 192);
        int cq = (int)(p % 192);
        u16x4 o = {0, 0, 0, 0};
        if (row < DINPROJ) {
            f4 v = *(const f4*)&W_in[(long)row * DM + cq * 4];
            o[0] = f2bf(v[0]); o[1] = f2bf(v[1]); o[2] = f2bf(v[2]); o[3] = f2bf(v[3]);
        }
        *(u16x4*)&winbf[p * 4] = o;
    } else if (q < NU + NW + NO) {
        long p = q - NU - NW;
        f4 v = *(const f4*)&W_out[p * 4];
        u16x4 o;
        o[0] = f2bf(v[0]); o[1] = f2bf(v[1]); o[2] = f2bf(v[2]); o[3] = f2bf(v[3]);
        *(u16x4*)&woutbf[p * 4] = o;
    }
}

// ---- in-proj GEMM: 512 threads / 8 waves, tile M128 x N256, BK=32,
//      3-buffer counted-vmcnt(3), XCD swizzle. nwg = 13*64 = 832 (%8==0).
__global__ __launch_bounds__(512) void gemm1_512(const ushort_t* __restrict__ A,
                                                 const ushort_t* __restrict__ B,
                                                 int K,
                                                 ushort_t* __restrict__ zbf,
                                                 ushort_t* __restrict__ xbcbf,
                                                 float* __restrict__ dtbT,
                                                 const float* __restrict__ dt_bias) {
    __shared__ __align__(16) ushort_t As[3][128 * 32];  // 8KB each
    __shared__ __align__(16) ushort_t Bs[3][256 * 32];  // 16KB each
    int tid = threadIdx.x;
    int lane = tid & 63;
    int w = tid >> 6;          // 0..7
    int wr = w >> 2, wc = w & 3;
    int gx = gridDim.x;        // 13
    int nwg = gx * gridDim.y;  // 832
    int id = blockIdx.y * gx + blockIdx.x;
    int per = nwg >> 3;
    int id2 = (id & 7) * per + (id >> 3);
    int m0 = (id2 / gx) * 128;
    int n0 = (id2 % gx) * 256;
    int r16 = lane & 15, kg = lane >> 4;

    int row0 = tid >> 2, cof0 = (tid & 3) * 8;
    const ushort_t* abase = &A[(long)(m0 + row0) * K + cof0];
    const ushort_t* bb0 = &B[(long)(n0 + row0) * K + cof0];
    const ushort_t* bb1 = &B[(long)(n0 + row0 + 128) * K + cof0];

    f32x4 acc[4][4] = {};
    int nk = K >> 5;

    auto issue = [&](int t) {
        long k = (long)t << 5;
        int bi = t % 3;
        char* ab = (char*)&As[bi][0] + w * 1024;
        char* bb = (char*)&Bs[bi][0] + w * 1024;
        gl16(abase + k, ab);
        gl16(bb0 + k, bb);
        gl16(bb1 + k, bb + 8192);
    };
    issue(0);
    issue(1);

    for (int t = 0; t < nk; ++t) {
        if (t + 1 < nk) {
            asm volatile("s_waitcnt vmcnt(3)" ::: "memory");
        } else {
            asm volatile("s_waitcnt vmcnt(0)" ::: "memory");
        }
        __builtin_amdgcn_s_barrier();
        __builtin_amdgcn_sched_barrier(0);
        if (t + 2 < nk) issue(t + 2);
        const ushort_t* Asc = &As[t % 3][0];
        const ushort_t* Bsc = &Bs[t % 3][0];
        bfx8 af[4], bfr[4];
#pragma unroll
        for (int i = 0; i < 4; ++i)
            af[i] = *(const bfx8*)&Asc[(wr * 64 + i * 16 + r16) * 32 + kg * 8];
#pragma unroll
        for (int j = 0; j < 4; ++j)
            bfr[j] = *(const bfx8*)&Bsc[(wc * 64 + j * 16 + r16) * 32 + kg * 8];
#pragma unroll
        for (int i = 0; i < 4; ++i)
#pragma unroll
            for (int j = 0; j < 4; ++j)
                acc[i][j] = __builtin_amdgcn_mfma_f32_16x16x32_bf16(af[i], bfr[j], acc[i][j], 0, 0, 0);
    }

#pragma unroll
    for (int i = 0; i < 4; ++i) {
        int rowb = m0 + wr * 64 + i * 16 + kg * 4;
#pragma unroll
        for (int j = 0; j < 4; ++j) {
            int col = n0 + wc * 64 + j * 16 + r16;
            if (col < DINNER) {  // z -> bf16
#pragma unroll
                for (int q = 0; q < 4; ++q)
                    zbf[(long)(rowb + q) * DINNER + col] = f2bf(acc[i][j][q]);
            } else if (col < 3200) {  // xBC -> bf16
#pragma unroll
                for (int q = 0; q < 4; ++q)
                    xbcbf[(long)(rowb + q) * XBCW + col - DINNER] = f2bf(acc[i][j][q]);
            } else if (col < DINPROJ) {  // dt -> softplus -> transposed
                int h = col - 3200;
                float bias = dt_bias[h];
#pragma unroll
                for (int q = 0; q < 4; ++q) {
                    float v = acc[i][j][q] + bias;
                    float d = (v > 20.f) ? v : log1pf(__expf(v));
                    dtbT[(long)h * BROWS + rowb + q] = d;
                }
            }
        }
    }
}

// ---- out-proj GEMM: 512 threads, tile M128 x N256, BK=32, 3-buffer vmcnt(3),
//      XCD swizzle. C f32 [M][ldc]. nwg = 3*64 = 192 (%8==0).
__global__ __launch_bounds__(512) void gemm2_512(const ushort_t* __restrict__ A,
                                                 const ushort_t* __restrict__ B,
                                                 float* __restrict__ C,
                                                 int K, int ldc) {
    __shared__ __align__(16) ushort_t As[3][128 * 32];
    __shared__ __align__(16) ushort_t Bs[3][256 * 32];
    int tid = threadIdx.x;
    int lane = tid & 63;
    int w = tid >> 6;
    int wr = w >> 2, wc = w & 3;
    int gx = gridDim.x;  // 3
    int nwg = gx * gridDim.y;
    int id = blockIdx.y * gx + blockIdx.x;
    int per = nwg >> 3;
    int id2 = (id & 7) * per + (id >> 3);
    int m0 = (id2 / gx) * 128;
    int n0 = (id2 % gx) * 256;
    int r16 = lane & 15, kg = lane >> 4;

    int row0 = tid >> 2, cof0 = (tid & 3) * 8;
    const ushort_t* abase = &A[(long)(m0 + row0) * K + cof0];
    const ushort_t* bb0 = &B[(long)(n0 + row0) * K + cof0];
    const ushort_t* bb1 = &B[(long)(n0 + row0 + 128) * K + cof0];

    f32x4 acc[4][4] = {};
    int nk = K >> 5;

    auto issue = [&](int t) {
        long k = (long)t << 5;
        int bi = t % 3;
        char* ab = (char*)&As[bi][0] + w * 1024;
        char* bb = (char*)&Bs[bi][0] + w * 1024;
        gl16(abase + k, ab);
        gl16(bb0 + k, bb);
        gl16(bb1 + k, bb + 8192);
    };
    issue(0);
    issue(1);

    for (int t = 0; t < nk; ++t) {
        if (t + 1 < nk) {
            asm volatile("s_waitcnt vmcnt(3)" ::: "memory");
        } else {
            asm volatile("s_waitcnt vmcnt(0)" ::: "memory");
        }
        __builtin_amdgcn_s_barrier();
        __builtin_amdgcn_sched_barrier(0);
        if (t + 2 < nk) issue(t + 2);
        const ushort_t* Asc = &As[t % 3][0];
        const ushort_t* Bsc = &Bs[t % 3][0];
        bfx8 af[4], bfr[4];
#pragma unroll
        for (int i = 0; i < 4; ++i)
            af[i] = *(const bfx8*)&Asc[(wr * 64 + i * 16 + r16) * 32 + kg * 8];
#pragma unroll
        for (int j = 0; j < 4; ++j)
            bfr[j] = *(const bfx8*)&Bsc[(wc * 64 + j * 16 + r16) * 32 + kg * 8];
#pragma unroll
        for (int i = 0; i < 4; ++i)
#pragma unroll
            for (int j = 0; j < 4; ++j)
                acc[i][j] = __builtin_amdgcn_mfma_f32_16x16x32_bf16(af[i], bfr[j], acc[i][j], 0, 0, 0);
    }

#pragma unroll
    for (int i = 0; i < 4; ++i) {
        int rowb = m0 + wr * 64 + i * 16 + kg * 4;
#pragma unroll
        for (int j = 0; j < 4; ++j) {
            int col = n0 + wc * 64 + j * 16 + r16;
#pragma unroll
            for (int q = 0; q < 4; ++q)
                C[(long)(rowb + q) * ldc + col] = acc[i][j][q];
        }
    }
}

// ---- fused conv(4)+silu + transpose: reads xbcrawbf, writes xbc AND xT (ch<1600) ----
__global__ __launch_bounds__(256) void convxt_kernel(const ushort_t* __restrict__ xin,
                                                     const float* __restrict__ cw,
                                                     const float* __restrict__ cb,
                                                     ushort_t* __restrict__ xbc,
                                                     ushort_t* __restrict__ xT) {
    __shared__ ushort_t tile[64][PADB];
    int rt = blockIdx.x;  // 128 row-tiles
    int ct = blockIdx.y;  // 26 ch-tiles
    int t = threadIdx.x;
#pragma unroll
    for (int i = 0; i < 2; ++i) {
        int q = t + 256 * i;
        int r = q >> 3, c8 = q & 7;
        int row = rt * 64 + r;
        int b = row >> 12, l = row & 4095;
        int ch = ct * 64 + c8 * 8;
        float a[8];
#pragma unroll
        for (int j = 0; j < 8; ++j) a[j] = cb[ch + j];
#pragma unroll
        for (int k = 0; k < 4; ++k) {
            int ll = l - 3 + k;
            if (ll >= 0) {
                u16x8 v = *(const u16x8*)&xin[(long)(b * 4096 + ll) * XBCW + ch];
#pragma unroll
                for (int j = 0; j < 8; ++j) a[j] += cw[(ch + j) * 4 + k] * bf2f(v[j]);
            }
        }
        u16x8 o;
#pragma unroll
        for (int j = 0; j < 8; ++j) {
            float s = a[j] / (1.f + __expf(-a[j]));
            o[j] = f2bf(s);
        }
        *(u16x8*)&xbc[(long)row * XBCW + ch] = o;
        *(u16x8*)&tile[r][c8 * 8] = o;
    }
    __syncthreads();
    if (ct < 25) {
#pragma unroll
        for (int i = 0; i < 2; ++i) {
            int q = t + 256 * i;
            int ch = q >> 3, sg = q & 7;
            u16x8 o;
#pragma unroll
            for (int k = 0; k < 8; ++k) o[k] = tile[sg * 8 + k][ch];
            *(u16x8*)&xT[(long)(ct * 64 + ch) * BROWS + rt * 64 + sg * 8] = o;
        }
    }
}

// ---- per-chunk cumsum of A*dt via wave scan ----
__global__ __launch_bounds__(256) void acs_kernel(const float* __restrict__ dtbT,
                                                  const float* __restrict__ A_log,
                                                  float* __restrict__ acs,
                                                  float* __restrict__ Tsum) {
    int bh = blockIdx.x;
    int b = bh / NH, h = bh % NH;
    int t = threadIdx.x;
    int lane = t & 63;
    float A = -__expf(A_log[h]);
    const float* dp = &dtbT[(long)h * BROWS + b * 4096];
#pragma unroll
    for (int it = 0; it < 16; ++it) {
        int c = (t >> 6) + 4 * it;
        float v = A * dp[c * 64 + lane];
#pragma unroll
        for (int off = 1; off < 64; off <<= 1) {
            float u = __shfl_up(v, off, 64);
            if (lane >= off) v += u;
        }
        acs[((long)bh * NCHUNK + c) * 64 + lane] = v;
        if (lane == 63) Tsum[bh * NCHUNK + c] = v;
    }
}

// ---- phase A (MFMA): states[p][n] = sum_l (x*dt*decay)[l][p] * B[l][n] -> bf16 ----
__global__ __launch_bounds__(256) void states_kernel(const ushort_t* __restrict__ xT,
                                                     const float* __restrict__ dtbT,
                                                     const float* __restrict__ acs,
                                                     const float* __restrict__ Tsum,
                                                     ushort_t* __restrict__ states) {
    int h = blockIdx.x, c = blockIdx.y, b = blockIdx.z;
    __shared__ __align__(16) ushort_t Wt[64 * PADB];
    __shared__ __align__(16) ushort_t Bt[64 * PADB];
    __shared__ float sDec[64];
    int t = threadIdx.x;
    long rowg0 = (long)b * 4096 + c * 64;
    long acsb = ((long)(b * NH + h) * NCHUNK + c) * 64;
    float T = Tsum[(b * NH + h) * NCHUNK + c];
    if (t < 64)
        sDec[t] = dtbT[(long)h * BROWS + rowg0 + t] * __expf(T - acs[acsb + t]);
    __syncthreads();
#pragma unroll
    for (int i = 0; i < 2; ++i) {
        int q = t + 256 * i;
        int p = q >> 3, sg = q & 7;
        u16x8 xv = *(const u16x8*)&xT[(long)(h * 64 + p) * BROWS + rowg0 + sg * 8];
        u16x8 wv;
#pragma unroll
        for (int j = 0; j < 8; ++j) wv[j] = f2bf(bf2f(xv[j]) * sDec[sg * 8 + j]);
        *(u16x8*)&Wt[p * PADB + sg * 8] = wv;
        *(u16x8*)&Bt[p * PADB + sg * 8] =
            *(const u16x8*)&xT[(long)(DINNER + p) * BROWS + rowg0 + sg * 8];
    }
    __syncthreads();
    int w = t >> 6, lane = t & 63;
    int r16 = lane & 15, kg = lane >> 4;
    bfx8 aw[2];
#pragma unroll
    for (int kk = 0; kk < 2; ++kk)
        aw[kk] = *(const bfx8*)&Wt[(w * 16 + r16) * PADB + kk * 32 + kg * 8];
    f32x4 acc[4] = {};
#pragma unroll
    for (int j = 0; j < 4; ++j)
#pragma unroll
        for (int kk = 0; kk < 2; ++kk) {
            bfx8 bb = *(const bfx8*)&Bt[(j * 16 + r16) * PADB + kk * 32 + kg * 8];
            acc[j] = __builtin_amdgcn_mfma_f32_16x16x32_bf16(aw[kk], bb, acc[j], 0, 0, 0);
        }
    __syncthreads();
#pragma unroll
    for (int j = 0; j < 4; ++j)
#pragma unroll
        for (int q = 0; q < 4; ++q)
            Wt[(w * 16 + kg * 4 + q) * PADB + j * 16 + r16] = f2bf(acc[j][q]);
    __syncthreads();
    long ob = ((long)(b * NH + h) * NCHUNK + c) * 4096;
#pragma unroll
    for (int i = 0; i < 2; ++i) {
        int q = t + 256 * i;
        int p = q >> 3, sg = q & 7;
        *(u16x8*)&states[ob + p * 64 + sg * 8] = *(const u16x8*)&Wt[p * PADB + sg * 8];
    }
}

// ---- sequential chunk scan ----
__global__ __launch_bounds__(256) void scan_kernel(const float* __restrict__ Tsum,
                                                   ushort_t* __restrict__ states) {
    int e = blockIdx.x * 256 + threadIdx.x;
    int h = blockIdx.y, b = blockIdx.z;
    long base = ((long)(b * NH + h)) * NCHUNK * 4096 + e;
    const float* Tp = &Tsum[(b * NH + h) * NCHUNK];
    float acc = 0.f;
    for (int c = 0; c < NCHUNK; ++c) {
        float cur = bf2f(states[base + (long)c * 4096]);
        states[base + (long)c * 4096] = f2bf(acc);
        acc = __expf(Tp[c]) * acc + cur;
    }
}

// ---- phase C (MFMA): Y = (C.B^T . Lm) @ xd + exp(acs) * (C @ Sprev^T) -> bf16 ybuf ----
__global__ __launch_bounds__(256) void yfull_kernel(const ushort_t* __restrict__ xbc,
                                                    const ushort_t* __restrict__ xT,
                                                    const float* __restrict__ dtbT,
                                                    const float* __restrict__ acs,
                                                    const ushort_t* __restrict__ sprev,
                                                    ushort_t* __restrict__ ybuf) {
    int h = blockIdx.x, c = blockIdx.y, b = blockIdx.z;
    __shared__ __align__(16) ushort_t Cb[64 * PADB];
    __shared__ __align__(16) ushort_t Bb[64 * PADB];
    __shared__ __align__(16) ushort_t Xt[64 * PADB];
    __shared__ __align__(16) ushort_t Sp[64 * PADB];
    __shared__ __align__(16) ushort_t Sm[64 * PADB];
    __shared__ float sAcs[64], sE[64], sDt[64];
    int t = threadIdx.x;
    long rowg0 = (long)b * 4096 + c * 64;
    long acsb = ((long)(b * NH + h) * NCHUNK + c) * 64;
    long spb = ((long)(b * NH + h) * NCHUNK + c) * 4096;
    if (t < 64) {
        float a = acs[acsb + t];
        sAcs[t] = a;
        sE[t] = __expf(a);
        sDt[t] = dtbT[(long)h * BROWS + rowg0 + t];
    }
    __syncthreads();
#pragma unroll
    for (int i = 0; i < 2; ++i) {
        int q = t + 256 * i;
        int l = q >> 3, sg = q & 7;
        const ushort_t* rp = &xbc[(rowg0 + l) * (long)XBCW];
        *(u16x8*)&Cb[l * PADB + sg * 8] = *(const u16x8*)&rp[1600 + sg * 8];
        *(u16x8*)&Bb[l * PADB + sg * 8] = *(const u16x8*)&rp[DINNER + sg * 8];
        u16x8 xv = *(const u16x8*)&xT[(long)(h * 64 + l) * BROWS + rowg0 + sg * 8];
        u16x8 xo;
#pragma unroll
        for (int j = 0; j < 8; ++j) xo[j] = f2bf(bf2f(xv[j]) * sDt[sg * 8 + j]);
        *(u16x8*)&Xt[l * PADB + sg * 8] = xo;
        *(u16x8*)&Sp[l * PADB + sg * 8] = *(const u16x8*)&sprev[spb + l * 64 + sg * 8];
    }
    __syncthreads();
    int w = t >> 6, lane = t & 63;
    int r16 = lane & 15, kg = lane >> 4;
    bfx8 ac[2];
#pragma unroll
    for (int kk = 0; kk < 2; ++kk)
        ac[kk] = *(const bfx8*)&Cb[(w * 16 + r16) * PADB + kk * 32 + kg * 8];
    f32x4 s_acc[4] = {};
#pragma unroll
    for (int j = 0; j < 4; ++j)
#pragma unroll
        for (int kk = 0; kk < 2; ++kk) {
            bfx8 bb = *(const bfx8*)&Bb[(j * 16 + r16) * PADB + kk * 32 + kg * 8];
            s_acc[j] = __builtin_amdgcn_mfma_f32_16x16x32_bf16(ac[kk], bb, s_acc[j], 0, 0, 0);
        }
#pragma unroll
    for (int j = 0; j < 4; ++j)
#pragma unroll
        for (int q = 0; q < 4; ++q) {
            int l = w * 16 + kg * 4 + q;
            int s = j * 16 + r16;
            float v = s_acc[j][q];
            v = (s <= l) ? v * __expf(sAcs[l] - sAcs[s]) : 0.f;
            Sm[l * PADB + s] = f2bf(v);
        }
    __syncthreads();
    bfx8 as[2];
#pragma unroll
    for (int kk = 0; kk < 2; ++kk)
        as[kk] = *(const bfx8*)&Sm[(w * 16 + r16) * PADB + kk * 32 + kg * 8];
    f32x4 d_acc[4] = {}, o_acc[4] = {};
#pragma unroll
    for (int j = 0; j < 4; ++j)
#pragma unroll
        for (int kk = 0; kk < 2; ++kk) {
            bfx8 xb = *(const bfx8*)&Xt[(j * 16 + r16) * PADB + kk * 32 + kg * 8];
            d_acc[j] = __builtin_amdgcn_mfma_f32_16x16x32_bf16(as[kk], xb, d_acc[j], 0, 0, 0);
            bfx8 sb = *(const bfx8*)&Sp[(j * 16 + r16) * PADB + kk * 32 + kg * 8];
            o_acc[j] = __builtin_amdgcn_mfma_f32_16x16x32_bf16(ac[kk], sb, o_acc[j], 0, 0, 0);
        }
#pragma unroll
    for (int j = 0; j < 4; ++j)
#pragma unroll
        for (int q = 0; q < 4; ++q) {
            int l = w * 16 + kg * 4 + q;
            int p = j * 16 + r16;
            Bb[l * PADB + p] = f2bf(d_acc[j][q] + sE[l] * o_acc[j][q]);
        }
    __syncthreads();
#pragma unroll
    for (int i = 0; i < 2; ++i) {
        int q = t + 256 * i;
        int l = q >> 3, sg = q & 7;
        *(u16x8*)&ybuf[(rowg0 + l) * (long)DINNER + h * 64 + sg * 8] =
            *(const u16x8*)&Bb[l * PADB + sg * 8];
    }
}

// ---- gated RMS norm -> bf16 ----
__global__ __launch_bounds__(256) void norm_kernel(const ushort_t* __restrict__ ybuf,
                                                   const ushort_t* __restrict__ xbc,
                                                   const ushort_t* __restrict__ zbf,
                                                   const float* __restrict__ Dp,
                                                   const float* __restrict__ normw,
                                                   ushort_t* __restrict__ ybf) {
    int row = blockIdx.x;
    int t = threadIdx.x;
    float g[6];
    float ss = 0.f;
#pragma unroll
    for (int i = 0; i < 6; ++i) {
        int j = t + 256 * i;
        int h = j >> 6;
        float x = bf2f(xbc[(long)row * XBCW + j]);
        float yy = bf2f(ybuf[(long)row * DINNER + j]) + x * Dp[h];
        float z = bf2f(zbf[(long)row * DINNER + j]);
        float gz = z / (1.f + __expf(-z));
        float v = yy * gz;
        g[i] = v;
        ss += v * v;
    }
#pragma unroll
    for (int o = 32; o > 0; o >>= 1) ss += __shfl_xor(ss, o, 64);
    __shared__ float wsum[4];
    __shared__ float sscale;
    int w = t >> 6;
    if ((t & 63) == 0) wsum[w] = ss;
    __syncthreads();
    if (t == 0) {
        float tot = wsum[0] + wsum[1] + wsum[2] + wsum[3];
        sscale = rsqrtf(tot / (float)DINNER + 1e-5f);
    }
    __syncthreads();
    float sc = sscale;
#pragma unroll
    for (int i = 0; i < 6; ++i) {
        int j = t + 256 * i;
        ybf[(long)row * DINNER + j] = f2bf(g[i] * sc * normw[j]);
    }
}

extern "C" void kernel_launch(void* const* d_in, const int* in_sizes, int n_in,
                              void* d_out, int out_size, void* d_ws, size_t ws_size,
                              hipStream_t stream) {
    const float* u = (const float*)d_in[0];
    const float* W_in = (const float*)d_in[1];
    const float* conv_w = (const float*)d_in[2];
    const float* conv_b = (const float*)d_in[3];
    const float* dt_bias = (const float*)d_in[4];
    const float* A_log = (const float*)d_in[5];
    const float* Dp = (const float*)d_in[6];
    const float* norm_w = (const float*)d_in[7];
    const float* W_out = (const float*)d_in[8];
    float* out = (float*)d_out;

    char* ws = (char*)d_ws;
    size_t off = 0;
    auto alloc = [&](size_t bytes) {
        void* p = ws + off;
        off += (bytes + 255) & ~(size_t)255;
        return p;
    };
    ushort_t* zbf = (ushort_t*)alloc((size_t)BROWS * DINNER * 2);      // 25.2 MB
    ushort_t* xbcrawbf = (ushort_t*)alloc((size_t)BROWS * XBCW * 2);   // 27.3 MB
    ushort_t* xbc = (ushort_t*)alloc((size_t)BROWS * XBCW * 2);        // 27.3 MB
    ushort_t* xT = (ushort_t*)alloc((size_t)1600 * BROWS * 2);         // 26.2 MB
    float* dtbT = (float*)alloc((size_t)NH * BROWS * 4);               // 0.79 MB
    float* acs = (float*)alloc((size_t)2 * NH * NCHUNK * 64 * 4);      // 0.79 MB
    float* Tsum = (float*)alloc((size_t)2 * NH * NCHUNK * 4);          // 12 KB
    ushort_t* states = (ushort_t*)alloc((size_t)2 * NH * NCHUNK * 4096 * 2);  // 25.2 MB
    ushort_t* ybuf = (ushort_t*)alloc((size_t)BROWS * DINNER * 2);     // 25.2 MB
    ushort_t* woutbf = (ushort_t*)alloc((size_t)DM * DINNER * 2);      // 2.4 MB (own slot)
    // aliases with disjoint lifetimes:
    ushort_t* ybf = xbcrawbf;             // xbcrawbf dead after convxt
    ushort_t* ubf = ybuf;                 // u-bf16 dead after gemm1; ybuf written in yfull
    ushort_t* winbf = states;             // W_in-bf16 dead after gemm1; states written after

    if (off > ws_size) {
        fill_kernel<<<(out_size + 255) / 256, 256, 0, stream>>>(out, out_size, 12345.0f);
        return;
    }

    // all input conversions in one launch
    {
        const long NU = (long)BROWS * DM / 4;
        const long NW = (long)NPAD1 * 192;
        const long NO = (long)DM * DINNER / 4;
        long nblk = (NU + NW + NO + 255) / 256;
        cvt_all<<<(int)nblk, 256, 0, stream>>>(u, W_in, W_out, ubf, winbf, woutbf);
    }

    // in-projection, 512-thread M128xN256 tile, split epilogue
    gemm1_512<<<dim3(13, 64), 512, 0, stream>>>(ubf, winbf, DM, zbf, xbcrawbf, dtbT, dt_bias);

    // fused conv+silu+transpose
    convxt_kernel<<<dim3(128, 26), 256, 0, stream>>>(xbcrawbf, conv_w, conv_b, xbc, xT);

    acs_kernel<<<2 * NH, 256, 0, stream>>>(dtbT, A_log, acs, Tsum);
    states_kernel<<<dim3(NH, NCHUNK, 2), 256, 0, stream>>>(xT, dtbT, acs, Tsum, states);
    scan_kernel<<<dim3(16, NH, 2), 256, 0, stream>>>(Tsum, states);
    yfull_kernel<<<dim3(NH, NCHUNK, 2), 256, 0, stream>>>(xbc, xT, dtbT, acs, states, ybuf);

    norm_kernel<<<BROWS, 256, 0, stream>>>(ybuf, xbc, zbf, Dp, norm_w, ybf);

    // out-projection, 512-thread M128xN256 tile
    gemm2_512<<<dim3(3, 64), 512, 0, stream>>>(ybf, woutbf, out, DINNER, DM);
}

// Round 21
// 247.196 us; speedup vs baseline: 1.0347x; 1.0347x over previous
//
#include <hip/hip_runtime.h>

typedef __attribute__((ext_vector_type(4))) float f4;
typedef __attribute__((ext_vector_type(8))) short bfx8;
typedef __attribute__((ext_vector_type(4))) float f32x4;
typedef __attribute__((ext_vector_type(4))) unsigned int u32x4;
typedef __attribute__((ext_vector_type(4))) unsigned short u16x4;
typedef __attribute__((ext_vector_type(8))) unsigned short u16x8;
typedef unsigned short ushort_t;

#define DM 768
#define DINNER 1536
#define NH 24
#define XBCW 1664
#define DINPROJ 3224
#define NPAD1 3328
#define NCHUNK 64
#define BROWS 8192
#define PADB 72  // bf16 LDS row stride for 64-wide tiles

__device__ inline ushort_t f2bf(float f) {
    unsigned u = __builtin_bit_cast(unsigned, f);
    unsigned r = (u + 0x7FFF + ((u >> 16) & 1)) >> 16;
    return (ushort_t)r;
}
__device__ inline float bf2f(ushort_t u) {
    return __builtin_bit_cast(float, (unsigned)u << 16);
}
// direct global->LDS 16B staging. dst wave-uniform; HW adds lane*16.
__device__ inline void gl16(const void* g, void* l) {
    __builtin_amdgcn_global_load_lds((const __attribute__((address_space(1))) void*)g,
                                     (__attribute__((address_space(3))) void*)l, 16, 0, 0);
}

__global__ __launch_bounds__(256) void fill_kernel(float* out, int n, float v) {
    int i = blockIdx.x * 256 + threadIdx.x;
    if (i < n) out[i] = v;
}

// ---- all three f32->bf16 input conversions in one launch ----
__global__ __launch_bounds__(256) void cvt_all(const float* __restrict__ u,
                                               const float* __restrict__ W_in,
                                               const float* __restrict__ W_out,
                                               ushort_t* __restrict__ ubf,
                                               ushort_t* __restrict__ winbf,
                                               ushort_t* __restrict__ woutbf) {
    const long NU = (long)BROWS * DM / 4;
    const long NW = (long)NPAD1 * 192;
    const long NO = (long)DM * DINNER / 4;
    long q = (long)blockIdx.x * 256 + threadIdx.x;
    if (q < NU) {
        f4 v = *(const f4*)&u[q * 4];
        u16x4 o;
        o[0] = f2bf(v[0]); o[1] = f2bf(v[1]); o[2] = f2bf(v[2]); o[3] = f2bf(v[3]);
        *(u16x4*)&ubf[q * 4] = o;
    } else if (q < NU + NW) {
        long p = q - NU;
        int row = (int)(p / 192);
        int cq = (int)(p % 192);
        u16x4 o = {0, 0, 0, 0};
        if (row < DINPROJ) {
            f4 v = *(const f4*)&W_in[(long)row * DM + cq * 4];
            o[0] = f2bf(v[0]); o[1] = f2bf(v[1]); o[2] = f2bf(v[2]); o[3] = f2bf(v[3]);
        }
        *(u16x4*)&winbf[p * 4] = o;
    } else if (q < NU + NW + NO) {
        long p = q - NU - NW;
        f4 v = *(const f4*)&W_out[p * 4];
        u16x4 o;
        o[0] = f2bf(v[0]); o[1] = f2bf(v[1]); o[2] = f2bf(v[2]); o[3] = f2bf(v[3]);
        *(u16x4*)&woutbf[p * 4] = o;
    }
}

// ---- in-proj GEMM: 512 threads / 8 waves, tile M128 x N256, BK=32,
//      3-buffer counted-vmcnt(3), XCD swizzle. nwg = 13*64 = 832 (%8==0).
__global__ __launch_bounds__(512) void gemm1_512(const ushort_t* __restrict__ A,
                                                 const ushort_t* __restrict__ B,
                                                 int K,
                                                 ushort_t* __restrict__ zbf,
                                                 ushort_t* __restrict__ xbcbf,
                                                 float* __restrict__ dtbT,
                                                 const float* __restrict__ dt_bias) {
    __shared__ __align__(16) ushort_t As[3][128 * 32];  // 8KB each
    __shared__ __align__(16) ushort_t Bs[3][256 * 32];  // 16KB each
    int tid = threadIdx.x;
    int lane = tid & 63;
    int w = tid >> 6;          // 0..7
    int wr = w >> 2, wc = w & 3;
    int gx = gridDim.x;        // 13
    int nwg = gx * gridDim.y;  // 832
    int id = blockIdx.y * gx + blockIdx.x;
    int per = nwg >> 3;
    int id2 = (id & 7) * per + (id >> 3);
    int m0 = (id2 / gx) * 128;
    int n0 = (id2 % gx) * 256;
    int r16 = lane & 15, kg = lane >> 4;

    int row0 = tid >> 2, cof0 = (tid & 3) * 8;
    const ushort_t* abase = &A[(long)(m0 + row0) * K + cof0];
    const ushort_t* bb0 = &B[(long)(n0 + row0) * K + cof0];
    const ushort_t* bb1 = &B[(long)(n0 + row0 + 128) * K + cof0];

    f32x4 acc[4][4] = {};
    int nk = K >> 5;

    auto issue = [&](int t) {
        long k = (long)t << 5;
        int bi = t % 3;
        char* ab = (char*)&As[bi][0] + w * 1024;
        char* bb = (char*)&Bs[bi][0] + w * 1024;
        gl16(abase + k, ab);
        gl16(bb0 + k, bb);
        gl16(bb1 + k, bb + 8192);
    };
    issue(0);
    issue(1);

    for (int t = 0; t < nk; ++t) {
        if (t + 1 < nk) {
            asm volatile("s_waitcnt vmcnt(3)" ::: "memory");
        } else {
            asm volatile("s_waitcnt vmcnt(0)" ::: "memory");
        }
        __builtin_amdgcn_s_barrier();
        __builtin_amdgcn_sched_barrier(0);
        if (t + 2 < nk) issue(t + 2);
        const ushort_t* Asc = &As[t % 3][0];
        const ushort_t* Bsc = &Bs[t % 3][0];
        bfx8 af[4], bfr[4];
#pragma unroll
        for (int i = 0; i < 4; ++i)
            af[i] = *(const bfx8*)&Asc[(wr * 64 + i * 16 + r16) * 32 + kg * 8];
#pragma unroll
        for (int j = 0; j < 4; ++j)
            bfr[j] = *(const bfx8*)&Bsc[(wc * 64 + j * 16 + r16) * 32 + kg * 8];
#pragma unroll
        for (int i = 0; i < 4; ++i)
#pragma unroll
            for (int j = 0; j < 4; ++j)
                acc[i][j] = __builtin_amdgcn_mfma_f32_16x16x32_bf16(af[i], bfr[j], acc[i][j], 0, 0, 0);
    }

#pragma unroll
    for (int i = 0; i < 4; ++i) {
        int rowb = m0 + wr * 64 + i * 16 + kg * 4;
#pragma unroll
        for (int j = 0; j < 4; ++j) {
            int col = n0 + wc * 64 + j * 16 + r16;
            if (col < DINNER) {  // z -> bf16
#pragma unroll
                for (int q = 0; q < 4; ++q)
                    zbf[(long)(rowb + q) * DINNER + col] = f2bf(acc[i][j][q]);
            } else if (col < 3200) {  // xBC -> bf16
#pragma unroll
                for (int q = 0; q < 4; ++q)
                    xbcbf[(long)(rowb + q) * XBCW + col - DINNER] = f2bf(acc[i][j][q]);
            } else if (col < DINPROJ) {  // dt -> softplus -> transposed
                int h = col - 3200;
                float bias = dt_bias[h];
#pragma unroll
                for (int q = 0; q < 4; ++q) {
                    float v = acc[i][j][q] + bias;
                    float d = (v > 20.f) ? v : log1pf(__expf(v));
                    dtbT[(long)h * BROWS + rowb + q] = d;
                }
            }
        }
    }
}

// ---- out-proj GEMM C[M][ldc](f32) = A * B^T, 128x128, BK=32, 3-buffer counted-vmcnt ----
__global__ __launch_bounds__(256) void gemm_bt(const ushort_t* __restrict__ A,
                                               const ushort_t* __restrict__ B,
                                               float* __restrict__ C,
                                               int K, int ldc) {
    __shared__ __align__(16) ushort_t As[3][128 * 32];
    __shared__ __align__(16) ushort_t Bs[3][128 * 32];
    int tid = threadIdx.x;
    int lane = tid & 63;
    int w = tid >> 6;
    int wr = w >> 1, wc = w & 1;
    int gx = gridDim.x;
    int nwg = gx * gridDim.y;
    int id = blockIdx.y * gx + blockIdx.x;
    int per = nwg >> 3;
    int id2 = (id & 7) * per + (id >> 3);
    int m0 = (id2 / gx) * 128;
    int n0 = (id2 % gx) * 128;
    int r16 = lane & 15, kg = lane >> 4;

    int row0 = tid >> 2, cof0 = (tid & 3) * 8;
    const ushort_t* a0 = &A[(long)(m0 + row0) * K + cof0];
    const ushort_t* a1 = &A[(long)(m0 + row0 + 64) * K + cof0];
    const ushort_t* b0 = &B[(long)(n0 + row0) * K + cof0];
    const ushort_t* b1 = &B[(long)(n0 + row0 + 64) * K + cof0];

    f32x4 acc[4][4] = {};
    int nk = K >> 5;

    auto issue = [&](int t) {
        int k = t << 5;
        int bi = t % 3;
        char* ab = (char*)&As[bi][0] + w * 1024;
        char* bb = (char*)&Bs[bi][0] + w * 1024;
        gl16(a0 + k, ab); gl16(a1 + k, ab + 4096);
        gl16(b0 + k, bb); gl16(b1 + k, bb + 4096);
    };
    issue(0);
    issue(1);

    for (int t = 0; t < nk; ++t) {
        if (t + 1 < nk) {
            asm volatile("s_waitcnt vmcnt(4)" ::: "memory");
        } else {
            asm volatile("s_waitcnt vmcnt(0)" ::: "memory");
        }
        __builtin_amdgcn_s_barrier();
        __builtin_amdgcn_sched_barrier(0);
        if (t + 2 < nk) issue(t + 2);
        const ushort_t* Asc = &As[t % 3][0];
        const ushort_t* Bsc = &Bs[t % 3][0];
        bfx8 af[4], bfr[4];
#pragma unroll
        for (int i = 0; i < 4; ++i) {
            af[i] = *(const bfx8*)&Asc[(wr * 64 + i * 16 + r16) * 32 + kg * 8];
            bfr[i] = *(const bfx8*)&Bsc[(wc * 64 + i * 16 + r16) * 32 + kg * 8];
        }
#pragma unroll
        for (int i = 0; i < 4; ++i)
#pragma unroll
            for (int j = 0; j < 4; ++j)
                acc[i][j] = __builtin_amdgcn_mfma_f32_16x16x32_bf16(af[i], bfr[j], acc[i][j], 0, 0, 0);
    }

#pragma unroll
    for (int i = 0; i < 4; ++i) {
        int rowb = m0 + wr * 64 + i * 16 + kg * 4;
#pragma unroll
        for (int j = 0; j < 4; ++j) {
            int col = n0 + wc * 64 + j * 16 + r16;
#pragma unroll
            for (int q = 0; q < 4; ++q)
                C[(long)(rowb + q) * ldc + col] = acc[i][j][q];
        }
    }
}

// ---- fused conv(4)+silu + transpose: reads xbcrawbf, writes xbc AND xT (ch<1600) ----
__global__ __launch_bounds__(256) void convxt_kernel(const ushort_t* __restrict__ xin,
                                                     const float* __restrict__ cw,
                                                     const float* __restrict__ cb,
                                                     ushort_t* __restrict__ xbc,
                                                     ushort_t* __restrict__ xT) {
    __shared__ ushort_t tile[64][PADB];
    int rt = blockIdx.x;  // 128 row-tiles
    int ct = blockIdx.y;  // 26 ch-tiles
    int t = threadIdx.x;
#pragma unroll
    for (int i = 0; i < 2; ++i) {
        int q = t + 256 * i;
        int r = q >> 3, c8 = q & 7;
        int row = rt * 64 + r;
        int b = row >> 12, l = row & 4095;
        int ch = ct * 64 + c8 * 8;
        float a[8];
#pragma unroll
        for (int j = 0; j < 8; ++j) a[j] = cb[ch + j];
#pragma unroll
        for (int k = 0; k < 4; ++k) {
            int ll = l - 3 + k;
            if (ll >= 0) {
                u16x8 v = *(const u16x8*)&xin[(long)(b * 4096 + ll) * XBCW + ch];
#pragma unroll
                for (int j = 0; j < 8; ++j) a[j] += cw[(ch + j) * 4 + k] * bf2f(v[j]);
            }
        }
        u16x8 o;
#pragma unroll
        for (int j = 0; j < 8; ++j) {
            float s = a[j] / (1.f + __expf(-a[j]));
            o[j] = f2bf(s);
        }
        *(u16x8*)&xbc[(long)row * XBCW + ch] = o;
        *(u16x8*)&tile[r][c8 * 8] = o;
    }
    __syncthreads();
    if (ct < 25) {
#pragma unroll
        for (int i = 0; i < 2; ++i) {
            int q = t + 256 * i;
            int ch = q >> 3, sg = q & 7;
            u16x8 o;
#pragma unroll
            for (int k = 0; k < 8; ++k) o[k] = tile[sg * 8 + k][ch];
            *(u16x8*)&xT[(long)(ct * 64 + ch) * BROWS + rt * 64 + sg * 8] = o;
        }
    }
}

// ---- per-chunk cumsum of A*dt via wave scan ----
__global__ __launch_bounds__(256) void acs_kernel(const float* __restrict__ dtbT,
                                                  const float* __restrict__ A_log,
                                                  float* __restrict__ acs,
                                                  float* __restrict__ Tsum) {
    int bh = blockIdx.x;
    int b = bh / NH, h = bh % NH;
    int t = threadIdx.x;
    int lane = t & 63;
    float A = -__expf(A_log[h]);
    const float* dp = &dtbT[(long)h * BROWS + b * 4096];
#pragma unroll
    for (int it = 0; it < 16; ++it) {
        int c = (t >> 6) + 4 * it;
        float v = A * dp[c * 64 + lane];
#pragma unroll
        for (int off = 1; off < 64; off <<= 1) {
            float u = __shfl_up(v, off, 64);
            if (lane >= off) v += u;
        }
        acs[((long)bh * NCHUNK + c) * 64 + lane] = v;
        if (lane == 63) Tsum[bh * NCHUNK + c] = v;
    }
}

// ---- phase A (MFMA): states[p][n] = sum_l (x*dt*decay)[l][p] * B[l][n] -> bf16 ----
__global__ __launch_bounds__(256) void states_kernel(const ushort_t* __restrict__ xT,
                                                     const float* __restrict__ dtbT,
                                                     const float* __restrict__ acs,
                                                     const float* __restrict__ Tsum,
                                                     ushort_t* __restrict__ states) {
    int h = blockIdx.x, c = blockIdx.y, b = blockIdx.z;
    __shared__ __align__(16) ushort_t Wt[64 * PADB];
    __shared__ __align__(16) ushort_t Bt[64 * PADB];
    __shared__ float sDec[64];
    int t = threadIdx.x;
    long rowg0 = (long)b * 4096 + c * 64;
    long acsb = ((long)(b * NH + h) * NCHUNK + c) * 64;
    float T = Tsum[(b * NH + h) * NCHUNK + c];
    if (t < 64)
        sDec[t] = dtbT[(long)h * BROWS + rowg0 + t] * __expf(T - acs[acsb + t]);
    __syncthreads();
#pragma unroll
    for (int i = 0; i < 2; ++i) {
        int q = t + 256 * i;
        int p = q >> 3, sg = q & 7;
        u16x8 xv = *(const u16x8*)&xT[(long)(h * 64 + p) * BROWS + rowg0 + sg * 8];
        u16x8 wv;
#pragma unroll
        for (int j = 0; j < 8; ++j) wv[j] = f2bf(bf2f(xv[j]) * sDec[sg * 8 + j]);
        *(u16x8*)&Wt[p * PADB + sg * 8] = wv;
        *(u16x8*)&Bt[p * PADB + sg * 8] =
            *(const u16x8*)&xT[(long)(DINNER + p) * BROWS + rowg0 + sg * 8];
    }
    __syncthreads();
    int w = t >> 6, lane = t & 63;
    int r16 = lane & 15, kg = lane >> 4;
    bfx8 aw[2];
#pragma unroll
    for (int kk = 0; kk < 2; ++kk)
        aw[kk] = *(const bfx8*)&Wt[(w * 16 + r16) * PADB + kk * 32 + kg * 8];
    f32x4 acc[4] = {};
#pragma unroll
    for (int j = 0; j < 4; ++j)
#pragma unroll
        for (int kk = 0; kk < 2; ++kk) {
            bfx8 bb = *(const bfx8*)&Bt[(j * 16 + r16) * PADB + kk * 32 + kg * 8];
            acc[j] = __builtin_amdgcn_mfma_f32_16x16x32_bf16(aw[kk], bb, acc[j], 0, 0, 0);
        }
    __syncthreads();
#pragma unroll
    for (int j = 0; j < 4; ++j)
#pragma unroll
        for (int q = 0; q < 4; ++q)
            Wt[(w * 16 + kg * 4 + q) * PADB + j * 16 + r16] = f2bf(acc[j][q]);
    __syncthreads();
    long ob = ((long)(b * NH + h) * NCHUNK + c) * 4096;
#pragma unroll
    for (int i = 0; i < 2; ++i) {
        int q = t + 256 * i;
        int p = q >> 3, sg = q & 7;
        *(u16x8*)&states[ob + p * 64 + sg * 8] = *(const u16x8*)&Wt[p * PADB + sg * 8];
    }
}

// ---- sequential chunk scan ----
__global__ __launch_bounds__(256) void scan_kernel(const float* __restrict__ Tsum,
                                                   ushort_t* __restrict__ states) {
    int e = blockIdx.x * 256 + threadIdx.x;
    int h = blockIdx.y, b = blockIdx.z;
    long base = ((long)(b * NH + h)) * NCHUNK * 4096 + e;
    const float* Tp = &Tsum[(b * NH + h) * NCHUNK];
    float acc = 0.f;
    for (int c = 0; c < NCHUNK; ++c) {
        float cur = bf2f(states[base + (long)c * 4096]);
        states[base + (long)c * 4096] = f2bf(acc);
        acc = __expf(Tp[c]) * acc + cur;
    }
}

// ---- phase C (MFMA): Y = (C.B^T . Lm) @ xd + exp(acs) * (C @ Sprev^T) -> bf16 ybuf ----
__global__ __launch_bounds__(256) void yfull_kernel(const ushort_t* __restrict__ xbc,
                                                    const ushort_t* __restrict__ xT,
                                                    const float* __restrict__ dtbT,
                                                    const float* __restrict__ acs,
                                                    const ushort_t* __restrict__ sprev,
                                                    ushort_t* __restrict__ ybuf) {
    int h = blockIdx.x, c = blockIdx.y, b = blockIdx.z;
    __shared__ __align__(16) ushort_t Cb[64 * PADB];
    __shared__ __align__(16) ushort_t Bb[64 * PADB];
    __shared__ __align__(16) ushort_t Xt[64 * PADB];
    __shared__ __align__(16) ushort_t Sp[64 * PADB];
    __shared__ __align__(16) ushort_t Sm[64 * PADB];
    __shared__ float sAcs[64], sE[64], sDt[64];
    int t = threadIdx.x;
    long rowg0 = (long)b * 4096 + c * 64;
    long acsb = ((long)(b * NH + h) * NCHUNK + c) * 64;
    long spb = ((long)(b * NH + h) * NCHUNK + c) * 4096;
    if (t < 64) {
        float a = acs[acsb + t];
        sAcs[t] = a;
        sE[t] = __expf(a);
        sDt[t] = dtbT[(long)h * BROWS + rowg0 + t];
    }
    __syncthreads();
#pragma unroll
    for (int i = 0; i < 2; ++i) {
        int q = t + 256 * i;
        int l = q >> 3, sg = q & 7;
        const ushort_t* rp = &xbc[(rowg0 + l) * (long)XBCW];
        *(u16x8*)&Cb[l * PADB + sg * 8] = *(const u16x8*)&rp[1600 + sg * 8];
        *(u16x8*)&Bb[l * PADB + sg * 8] = *(const u16x8*)&rp[DINNER + sg * 8];
        u16x8 xv = *(const u16x8*)&xT[(long)(h * 64 + l) * BROWS + rowg0 + sg * 8];
        u16x8 xo;
#pragma unroll
        for (int j = 0; j < 8; ++j) xo[j] = f2bf(bf2f(xv[j]) * sDt[sg * 8 + j]);
        *(u16x8*)&Xt[l * PADB + sg * 8] = xo;
        *(u16x8*)&Sp[l * PADB + sg * 8] = *(const u16x8*)&sprev[spb + l * 64 + sg * 8];
    }
    __syncthreads();
    int w = t >> 6, lane = t & 63;
    int r16 = lane & 15, kg = lane >> 4;
    bfx8 ac[2];
#pragma unroll
    for (int kk = 0; kk < 2; ++kk)
        ac[kk] = *(const bfx8*)&Cb[(w * 16 + r16) * PADB + kk * 32 + kg * 8];
    f32x4 s_acc[4] = {};
#pragma unroll
    for (int j = 0; j < 4; ++j)
#pragma unroll
        for (int kk = 0; kk < 2; ++kk) {
            bfx8 bb = *(const bfx8*)&Bb[(j * 16 + r16) * PADB + kk * 32 + kg * 8];
            s_acc[j] = __builtin_amdgcn_mfma_f32_16x16x32_bf16(ac[kk], bb, s_acc[j], 0, 0, 0);
        }
#pragma unroll
    for (int j = 0; j < 4; ++j)
#pragma unroll
        for (int q = 0; q < 4; ++q) {
            int l = w * 16 + kg * 4 + q;
            int s = j * 16 + r16;
            float v = s_acc[j][q];
            v = (s <= l) ? v * __expf(sAcs[l] - sAcs[s]) : 0.f;
            Sm[l * PADB + s] = f2bf(v);
        }
    __syncthreads();
    bfx8 as[2];
#pragma unroll
    for (int kk = 0; kk < 2; ++kk)
        as[kk] = *(const bfx8*)&Sm[(w * 16 + r16) * PADB + kk * 32 + kg * 8];
    f32x4 d_acc[4] = {}, o_acc[4] = {};
#pragma unroll
    for (int j = 0; j < 4; ++j)
#pragma unroll
        for (int kk = 0; kk < 2; ++kk) {
            bfx8 xb = *(const bfx8*)&Xt[(j * 16 + r16) * PADB + kk * 32 + kg * 8];
            d_acc[j] = __builtin_amdgcn_mfma_f32_16x16x32_bf16(as[kk], xb, d_acc[j], 0, 0, 0);
            bfx8 sb = *(const bfx8*)&Sp[(j * 16 + r16) * PADB + kk * 32 + kg * 8];
            o_acc[j] = __builtin_amdgcn_mfma_f32_16x16x32_bf16(ac[kk], sb, o_acc[j], 0, 0, 0);
        }
#pragma unroll
    for (int j = 0; j < 4; ++j)
#pragma unroll
        for (int q = 0; q < 4; ++q) {
            int l = w * 16 + kg * 4 + q;
            int p = j * 16 + r16;
            Bb[l * PADB + p] = f2bf(d_acc[j][q] + sE[l] * o_acc[j][q]);
        }
    __syncthreads();
#pragma unroll
    for (int i = 0; i < 2; ++i) {
        int q = t + 256 * i;
        int l = q >> 3, sg = q & 7;
        *(u16x8*)&ybuf[(rowg0 + l) * (long)DINNER + h * 64 + sg * 8] =
            *(const u16x8*)&Bb[l * PADB + sg * 8];
    }
}

// ---- gated RMS norm -> bf16 ----
__global__ __launch_bounds__(256) void norm_kernel(const ushort_t* __restrict__ ybuf,
                                                   const ushort_t* __restrict__ xbc,
                                                   const ushort_t* __restrict__ zbf,
                                                   const float* __restrict__ Dp,
                                                   const float* __restrict__ normw,
                                                   ushort_t* __restrict__ ybf) {
    int row = blockIdx.x;
    int t = threadIdx.x;
    float g[6];
    float ss = 0.f;
#pragma unroll
    for (int i = 0; i < 6; ++i) {
        int j = t + 256 * i;
        int h = j >> 6;
        float x = bf2f(xbc[(long)row * XBCW + j]);
        float yy = bf2f(ybuf[(long)row * DINNER + j]) + x * Dp[h];
        float z = bf2f(zbf[(long)row * DINNER + j]);
        float gz = z / (1.f + __expf(-z));
        float v = yy * gz;
        g[i] = v;
        ss += v * v;
    }
#pragma unroll
    for (int o = 32; o > 0; o >>= 1) ss += __shfl_xor(ss, o, 64);
    __shared__ float wsum[4];
    __shared__ float sscale;
    int w = t >> 6;
    if ((t & 63) == 0) wsum[w] = ss;
    __syncthreads();
    if (t == 0) {
        float tot = wsum[0] + wsum[1] + wsum[2] + wsum[3];
        sscale = rsqrtf(tot / (float)DINNER + 1e-5f);
    }
    __syncthreads();
    float sc = sscale;
#pragma unroll
    for (int i = 0; i < 6; ++i) {
        int j = t + 256 * i;
        ybf[(long)row * DINNER + j] = f2bf(g[i] * sc * normw[j]);
    }
}

extern "C" void kernel_launch(void* const* d_in, const int* in_sizes, int n_in,
                              void* d_out, int out_size, void* d_ws, size_t ws_size,
                              hipStream_t stream) {
    const float* u = (const float*)d_in[0];
    const float* W_in = (const float*)d_in[1];
    const float* conv_w = (const float*)d_in[2];
    const float* conv_b = (const float*)d_in[3];
    const float* dt_bias = (const float*)d_in[4];
    const float* A_log = (const float*)d_in[5];
    const float* Dp = (const float*)d_in[6];
    const float* norm_w = (const float*)d_in[7];
    const float* W_out = (const float*)d_in[8];
    float* out = (float*)d_out;

    char* ws = (char*)d_ws;
    size_t off = 0;
    auto alloc = [&](size_t bytes) {
        void* p = ws + off;
        off += (bytes + 255) & ~(size_t)255;
        return p;
    };
    ushort_t* zbf = (ushort_t*)alloc((size_t)BROWS * DINNER * 2);      // 25.2 MB
    ushort_t* xbcrawbf = (ushort_t*)alloc((size_t)BROWS * XBCW * 2);   // 27.3 MB
    ushort_t* xbc = (ushort_t*)alloc((size_t)BROWS * XBCW * 2);        // 27.3 MB
    ushort_t* xT = (ushort_t*)alloc((size_t)1600 * BROWS * 2);         // 26.2 MB
    float* dtbT = (float*)alloc((size_t)NH * BROWS * 4);               // 0.79 MB
    float* acs = (float*)alloc((size_t)2 * NH * NCHUNK * 64 * 4);      // 0.79 MB
    float* Tsum = (float*)alloc((size_t)2 * NH * NCHUNK * 4);          // 12 KB
    ushort_t* states = (ushort_t*)alloc((size_t)2 * NH * NCHUNK * 4096 * 2);  // 25.2 MB
    ushort_t* ybuf = (ushort_t*)alloc((size_t)BROWS * DINNER * 2);     // 25.2 MB
    ushort_t* woutbf = (ushort_t*)alloc((size_t)DM * DINNER * 2);      // 2.4 MB (own slot)
    // aliases with disjoint lifetimes:
    ushort_t* ybf = xbcrawbf;             // xbcrawbf dead after convxt
    ushort_t* ubf = ybuf;                 // u-bf16 dead after gemm1; ybuf written in yfull
    ushort_t* winbf = states;             // W_in-bf16 dead after gemm1; states written after

    if (off > ws_size) {
        fill_kernel<<<(out_size + 255) / 256, 256, 0, stream>>>(out, out_size, 12345.0f);
        return;
    }

    // all input conversions in one launch
    {
        const long NU = (long)BROWS * DM / 4;
        const long NW = (long)NPAD1 * 192;
        const long NO = (long)DM * DINNER / 4;
        long nblk = (NU + NW + NO + 255) / 256;
        cvt_all<<<(int)nblk, 256, 0, stream>>>(u, W_in, W_out, ubf, winbf, woutbf);
    }

    // in-projection, 512-thread M128xN256 tile, split epilogue
    gemm1_512<<<dim3(13, 64), 512, 0, stream>>>(ubf, winbf, DM, zbf, xbcrawbf, dtbT, dt_bias);

    // fused conv+silu+transpose
    convxt_kernel<<<dim3(128, 26), 256, 0, stream>>>(xbcrawbf, conv_w, conv_b, xbc, xT);

    acs_kernel<<<2 * NH, 256, 0, stream>>>(dtbT, A_log, acs, Tsum);
    states_kernel<<<dim3(NH, NCHUNK, 2), 256, 0, stream>>>(xT, dtbT, acs, Tsum, states);
    scan_kernel<<<dim3(16, NH, 2), 256, 0, stream>>>(Tsum, states);
    yfull_kernel<<<dim3(NH, NCHUNK, 2), 256, 0, stream>>>(xbc, xT, dtbT, acs, states, ybuf);

    norm_kernel<<<BROWS, 256, 0, stream>>>(ybuf, xbc, zbf, Dp, norm_w, ybf);

    // out-projection, 128x128 tile (384 blocks; best measured for N=768)
    gemm_bt<<<dim3(6, 64), 256, 0, stream>>>(ybf, woutbf, out, DINNER, DM);
}

// Round 22
// 244.605 us; speedup vs baseline: 1.0456x; 1.0106x over previous
//
#include <hip/hip_runtime.h>

typedef __attribute__((ext_vector_type(4))) float f4;
typedef __attribute__((ext_vector_type(8))) short bfx8;
typedef __attribute__((ext_vector_type(4))) float f32x4;
typedef __attribute__((ext_vector_type(4))) unsigned int u32x4;
typedef __attribute__((ext_vector_type(4))) unsigned short u16x4;
typedef __attribute__((ext_vector_type(8))) unsigned short u16x8;
typedef unsigned short ushort_t;

#define DM 768
#define DINNER 1536
#define NH 24
#define XBCW 1664
#define DINPROJ 3224
#define NPAD1 3328
#define NCHUNK 64
#define BROWS 8192
#define PADB 72  // bf16 LDS row stride for 64-wide tiles

__device__ inline ushort_t f2bf(float f) {
    unsigned u = __builtin_bit_cast(unsigned, f);
    unsigned r = (u + 0x7FFF + ((u >> 16) & 1)) >> 16;
    return (ushort_t)r;
}
__device__ inline float bf2f(ushort_t u) {
    return __builtin_bit_cast(float, (unsigned)u << 16);
}
// direct global->LDS 16B staging. dst wave-uniform; HW adds lane*16.
__device__ inline void gl16(const void* g, void* l) {
    __builtin_amdgcn_global_load_lds((const __attribute__((address_space(1))) void*)g,
                                     (__attribute__((address_space(3))) void*)l, 16, 0, 0);
}

__global__ __launch_bounds__(256) void fill_kernel(float* out, int n, float v) {
    int i = blockIdx.x * 256 + threadIdx.x;
    if (i < n) out[i] = v;
}

// ---- all three f32->bf16 input conversions in one launch ----
__global__ __launch_bounds__(256) void cvt_all(const float* __restrict__ u,
                                               const float* __restrict__ W_in,
                                               const float* __restrict__ W_out,
                                               ushort_t* __restrict__ ubf,
                                               ushort_t* __restrict__ winbf,
                                               ushort_t* __restrict__ woutbf) {
    const long NU = (long)BROWS * DM / 4;
    const long NW = (long)NPAD1 * 192;
    const long NO = (long)DM * DINNER / 4;
    long q = (long)blockIdx.x * 256 + threadIdx.x;
    if (q < NU) {
        f4 v = *(const f4*)&u[q * 4];
        u16x4 o;
        o[0] = f2bf(v[0]); o[1] = f2bf(v[1]); o[2] = f2bf(v[2]); o[3] = f2bf(v[3]);
        *(u16x4*)&ubf[q * 4] = o;
    } else if (q < NU + NW) {
        long p = q - NU;
        int row = (int)(p / 192);
        int cq = (int)(p % 192);
        u16x4 o = {0, 0, 0, 0};
        if (row < DINPROJ) {
            f4 v = *(const f4*)&W_in[(long)row * DM + cq * 4];
            o[0] = f2bf(v[0]); o[1] = f2bf(v[1]); o[2] = f2bf(v[2]); o[3] = f2bf(v[3]);
        }
        *(u16x4*)&winbf[p * 4] = o;
    } else if (q < NU + NW + NO) {
        long p = q - NU - NW;
        f4 v = *(const f4*)&W_out[p * 4];
        u16x4 o;
        o[0] = f2bf(v[0]); o[1] = f2bf(v[1]); o[2] = f2bf(v[2]); o[3] = f2bf(v[3]);
        *(u16x4*)&woutbf[p * 4] = o;
    }
}

// ---- in-proj GEMM: 512 threads / 8 waves, tile M128 x N256, BK=32,
//      2-buffer double-buffered gl16 (48KB LDS -> 3 blocks/CU), XCD swizzle.
__global__ __launch_bounds__(512) void gemm1_512(const ushort_t* __restrict__ A,
                                                 const ushort_t* __restrict__ B,
                                                 int K,
                                                 ushort_t* __restrict__ zbf,
                                                 ushort_t* __restrict__ xbcbf,
                                                 float* __restrict__ dtbT,
                                                 const float* __restrict__ dt_bias) {
    __shared__ __align__(16) ushort_t As[2][128 * 32];  // 8KB each
    __shared__ __align__(16) ushort_t Bs[2][256 * 32];  // 16KB each
    int tid = threadIdx.x;
    int lane = tid & 63;
    int w = tid >> 6;          // 0..7
    int wr = w >> 2, wc = w & 3;
    int gx = gridDim.x;        // 13
    int nwg = gx * gridDim.y;  // 832
    int id = blockIdx.y * gx + blockIdx.x;
    int per = nwg >> 3;
    int id2 = (id & 7) * per + (id >> 3);
    int m0 = (id2 / gx) * 128;
    int n0 = (id2 % gx) * 256;
    int r16 = lane & 15, kg = lane >> 4;

    int row0 = tid >> 2, cof0 = (tid & 3) * 8;
    const ushort_t* abase = &A[(long)(m0 + row0) * K + cof0];
    const ushort_t* bb0 = &B[(long)(n0 + row0) * K + cof0];
    const ushort_t* bb1 = &B[(long)(n0 + row0 + 128) * K + cof0];

    f32x4 acc[4][4] = {};
    int nk = K >> 5;

    auto issue = [&](int t, int buf) {
        long k = (long)t << 5;
        char* ab = (char*)&As[buf][0] + w * 1024;
        char* bb = (char*)&Bs[buf][0] + w * 1024;
        gl16(abase + k, ab);
        gl16(bb0 + k, bb);
        gl16(bb1 + k, bb + 8192);
    };
    issue(0, 0);
    asm volatile("s_waitcnt vmcnt(0)" ::: "memory");
    __builtin_amdgcn_s_barrier();

    int cur = 0;
    for (int t = 0; t < nk; ++t) {
        if (t + 1 < nk) issue(t + 1, cur ^ 1);  // loads fly under this tile's compute
        const ushort_t* Asc = &As[cur][0];
        const ushort_t* Bsc = &Bs[cur][0];
        bfx8 af[4], bfr[4];
#pragma unroll
        for (int i = 0; i < 4; ++i)
            af[i] = *(const bfx8*)&Asc[(wr * 64 + i * 16 + r16) * 32 + kg * 8];
#pragma unroll
        for (int j = 0; j < 4; ++j)
            bfr[j] = *(const bfx8*)&Bsc[(wc * 64 + j * 16 + r16) * 32 + kg * 8];
#pragma unroll
        for (int i = 0; i < 4; ++i)
#pragma unroll
            for (int j = 0; j < 4; ++j)
                acc[i][j] = __builtin_amdgcn_mfma_f32_16x16x32_bf16(af[i], bfr[j], acc[i][j], 0, 0, 0);
        asm volatile("s_waitcnt vmcnt(0)" ::: "memory");  // prefetch landed
        __builtin_amdgcn_s_barrier();                      // all reads of cur done
        cur ^= 1;
    }

#pragma unroll
    for (int i = 0; i < 4; ++i) {
        int rowb = m0 + wr * 64 + i * 16 + kg * 4;
#pragma unroll
        for (int j = 0; j < 4; ++j) {
            int col = n0 + wc * 64 + j * 16 + r16;
            if (col < DINNER) {  // z -> bf16
#pragma unroll
                for (int q = 0; q < 4; ++q)
                    zbf[(long)(rowb + q) * DINNER + col] = f2bf(acc[i][j][q]);
            } else if (col < 3200) {  // xBC -> bf16
#pragma unroll
                for (int q = 0; q < 4; ++q)
                    xbcbf[(long)(rowb + q) * XBCW + col - DINNER] = f2bf(acc[i][j][q]);
            } else if (col < DINPROJ) {  // dt -> softplus -> transposed
                int h = col - 3200;
                float bias = dt_bias[h];
#pragma unroll
                for (int q = 0; q < 4; ++q) {
                    float v = acc[i][j][q] + bias;
                    float d = (v > 20.f) ? v : log1pf(__expf(v));
                    dtbT[(long)h * BROWS + rowb + q] = d;
                }
            }
        }
    }
}

// ---- out-proj GEMM C[M][ldc](f32) = A * B^T, 128x128, BK=32, 3-buffer counted-vmcnt ----
__global__ __launch_bounds__(256) void gemm_bt(const ushort_t* __restrict__ A,
                                               const ushort_t* __restrict__ B,
                                               float* __restrict__ C,
                                               int K, int ldc) {
    __shared__ __align__(16) ushort_t As[3][128 * 32];
    __shared__ __align__(16) ushort_t Bs[3][128 * 32];
    int tid = threadIdx.x;
    int lane = tid & 63;
    int w = tid >> 6;
    int wr = w >> 1, wc = w & 1;
    int gx = gridDim.x;
    int nwg = gx * gridDim.y;
    int id = blockIdx.y * gx + blockIdx.x;
    int per = nwg >> 3;
    int id2 = (id & 7) * per + (id >> 3);
    int m0 = (id2 / gx) * 128;
    int n0 = (id2 % gx) * 128;
    int r16 = lane & 15, kg = lane >> 4;

    int row0 = tid >> 2, cof0 = (tid & 3) * 8;
    const ushort_t* a0 = &A[(long)(m0 + row0) * K + cof0];
    const ushort_t* a1 = &A[(long)(m0 + row0 + 64) * K + cof0];
    const ushort_t* b0 = &B[(long)(n0 + row0) * K + cof0];
    const ushort_t* b1 = &B[(long)(n0 + row0 + 64) * K + cof0];

    f32x4 acc[4][4] = {};
    int nk = K >> 5;

    auto issue = [&](int t) {
        int k = t << 5;
        int bi = t % 3;
        char* ab = (char*)&As[bi][0] + w * 1024;
        char* bb = (char*)&Bs[bi][0] + w * 1024;
        gl16(a0 + k, ab); gl16(a1 + k, ab + 4096);
        gl16(b0 + k, bb); gl16(b1 + k, bb + 4096);
    };
    issue(0);
    issue(1);

    for (int t = 0; t < nk; ++t) {
        if (t + 1 < nk) {
            asm volatile("s_waitcnt vmcnt(4)" ::: "memory");
        } else {
            asm volatile("s_waitcnt vmcnt(0)" ::: "memory");
        }
        __builtin_amdgcn_s_barrier();
        __builtin_amdgcn_sched_barrier(0);
        if (t + 2 < nk) issue(t + 2);
        const ushort_t* Asc = &As[t % 3][0];
        const ushort_t* Bsc = &Bs[t % 3][0];
        bfx8 af[4], bfr[4];
#pragma unroll
        for (int i = 0; i < 4; ++i) {
            af[i] = *(const bfx8*)&Asc[(wr * 64 + i * 16 + r16) * 32 + kg * 8];
            bfr[i] = *(const bfx8*)&Bsc[(wc * 64 + i * 16 + r16) * 32 + kg * 8];
        }
#pragma unroll
        for (int i = 0; i < 4; ++i)
#pragma unroll
            for (int j = 0; j < 4; ++j)
                acc[i][j] = __builtin_amdgcn_mfma_f32_16x16x32_bf16(af[i], bfr[j], acc[i][j], 0, 0, 0);
    }

#pragma unroll
    for (int i = 0; i < 4; ++i) {
        int rowb = m0 + wr * 64 + i * 16 + kg * 4;
#pragma unroll
        for (int j = 0; j < 4; ++j) {
            int col = n0 + wc * 64 + j * 16 + r16;
#pragma unroll
            for (int q = 0; q < 4; ++q)
                C[(long)(rowb + q) * ldc + col] = acc[i][j][q];
        }
    }
}

// ---- fused conv(4)+silu + transpose: reads xbcrawbf, writes xbc AND xT (ch<1600) ----
__global__ __launch_bounds__(256) void convxt_kernel(const ushort_t* __restrict__ xin,
                                                     const float* __restrict__ cw,
                                                     const float* __restrict__ cb,
                                                     ushort_t* __restrict__ xbc,
                                                     ushort_t* __restrict__ xT) {
    __shared__ ushort_t tile[64][PADB];
    int rt = blockIdx.x;  // 128 row-tiles
    int ct = blockIdx.y;  // 26 ch-tiles
    int t = threadIdx.x;
#pragma unroll
    for (int i = 0; i < 2; ++i) {
        int q = t + 256 * i;
        int r = q >> 3, c8 = q & 7;
        int row = rt * 64 + r;
        int b = row >> 12, l = row & 4095;
        int ch = ct * 64 + c8 * 8;
        float a[8];
#pragma unroll
        for (int j = 0; j < 8; ++j) a[j] = cb[ch + j];
#pragma unroll
        for (int k = 0; k < 4; ++k) {
            int ll = l - 3 + k;
            if (ll >= 0) {
                u16x8 v = *(const u16x8*)&xin[(long)(b * 4096 + ll) * XBCW + ch];
#pragma unroll
                for (int j = 0; j < 8; ++j) a[j] += cw[(ch + j) * 4 + k] * bf2f(v[j]);
            }
        }
        u16x8 o;
#pragma unroll
        for (int j = 0; j < 8; ++j) {
            float s = a[j] / (1.f + __expf(-a[j]));
            o[j] = f2bf(s);
        }
        *(u16x8*)&xbc[(long)row * XBCW + ch] = o;
        *(u16x8*)&tile[r][c8 * 8] = o;
    }
    __syncthreads();
    if (ct < 25) {
#pragma unroll
        for (int i = 0; i < 2; ++i) {
            int q = t + 256 * i;
            int ch = q >> 3, sg = q & 7;
            u16x8 o;
#pragma unroll
            for (int k = 0; k < 8; ++k) o[k] = tile[sg * 8 + k][ch];
            *(u16x8*)&xT[(long)(ct * 64 + ch) * BROWS + rt * 64 + sg * 8] = o;
        }
    }
}

// ---- per-chunk cumsum of A*dt via wave scan ----
__global__ __launch_bounds__(256) void acs_kernel(const float* __restrict__ dtbT,
                                                  const float* __restrict__ A_log,
                                                  float* __restrict__ acs,
                                                  float* __restrict__ Tsum) {
    int bh = blockIdx.x;
    int b = bh / NH, h = bh % NH;
    int t = threadIdx.x;
    int lane = t & 63;
    float A = -__expf(A_log[h]);
    const float* dp = &dtbT[(long)h * BROWS + b * 4096];
#pragma unroll
    for (int it = 0; it < 16; ++it) {
        int c = (t >> 6) + 4 * it;
        float v = A * dp[c * 64 + lane];
#pragma unroll
        for (int off = 1; off < 64; off <<= 1) {
            float u = __shfl_up(v, off, 64);
            if (lane >= off) v += u;
        }
        acs[((long)bh * NCHUNK + c) * 64 + lane] = v;
        if (lane == 63) Tsum[bh * NCHUNK + c] = v;
    }
}

// ---- phase A (MFMA): states[p][n] = sum_l (x*dt*decay)[l][p] * B[l][n] -> bf16 ----
__global__ __launch_bounds__(256) void states_kernel(const ushort_t* __restrict__ xT,
                                                     const float* __restrict__ dtbT,
                                                     const float* __restrict__ acs,
                                                     const float* __restrict__ Tsum,
                                                     ushort_t* __restrict__ states) {
    int h = blockIdx.x, c = blockIdx.y, b = blockIdx.z;
    __shared__ __align__(16) ushort_t Wt[64 * PADB];
    __shared__ __align__(16) ushort_t Bt[64 * PADB];
    __shared__ float sDec[64];
    int t = threadIdx.x;
    long rowg0 = (long)b * 4096 + c * 64;
    long acsb = ((long)(b * NH + h) * NCHUNK + c) * 64;
    float T = Tsum[(b * NH + h) * NCHUNK + c];
    if (t < 64)
        sDec[t] = dtbT[(long)h * BROWS + rowg0 + t] * __expf(T - acs[acsb + t]);
    __syncthreads();
#pragma unroll
    for (int i = 0; i < 2; ++i) {
        int q = t + 256 * i;
        int p = q >> 3, sg = q & 7;
        u16x8 xv = *(const u16x8*)&xT[(long)(h * 64 + p) * BROWS + rowg0 + sg * 8];
        u16x8 wv;
#pragma unroll
        for (int j = 0; j < 8; ++j) wv[j] = f2bf(bf2f(xv[j]) * sDec[sg * 8 + j]);
        *(u16x8*)&Wt[p * PADB + sg * 8] = wv;
        *(u16x8*)&Bt[p * PADB + sg * 8] =
            *(const u16x8*)&xT[(long)(DINNER + p) * BROWS + rowg0 + sg * 8];
    }
    __syncthreads();
    int w = t >> 6, lane = t & 63;
    int r16 = lane & 15, kg = lane >> 4;
    bfx8 aw[2];
#pragma unroll
    for (int kk = 0; kk < 2; ++kk)
        aw[kk] = *(const bfx8*)&Wt[(w * 16 + r16) * PADB + kk * 32 + kg * 8];
    f32x4 acc[4] = {};
#pragma unroll
    for (int j = 0; j < 4; ++j)
#pragma unroll
        for (int kk = 0; kk < 2; ++kk) {
            bfx8 bb = *(const bfx8*)&Bt[(j * 16 + r16) * PADB + kk * 32 + kg * 8];
            acc[j] = __builtin_amdgcn_mfma_f32_16x16x32_bf16(aw[kk], bb, acc[j], 0, 0, 0);
        }
    __syncthreads();
#pragma unroll
    for (int j = 0; j < 4; ++j)
#pragma unroll
        for (int q = 0; q < 4; ++q)
            Wt[(w * 16 + kg * 4 + q) * PADB + j * 16 + r16] = f2bf(acc[j][q]);
    __syncthreads();
    long ob = ((long)(b * NH + h) * NCHUNK + c) * 4096;
#pragma unroll
    for (int i = 0; i < 2; ++i) {
        int q = t + 256 * i;
        int p = q >> 3, sg = q & 7;
        *(u16x8*)&states[ob + p * 64 + sg * 8] = *(const u16x8*)&Wt[p * PADB + sg * 8];
    }
}

// ---- sequential chunk scan ----
__global__ __launch_bounds__(256) void scan_kernel(const float* __restrict__ Tsum,
                                                   ushort_t* __restrict__ states) {
    int e = blockIdx.x * 256 + threadIdx.x;
    int h = blockIdx.y, b = blockIdx.z;
    long base = ((long)(b * NH + h)) * NCHUNK * 4096 + e;
    const float* Tp = &Tsum[(b * NH + h) * NCHUNK];
    float acc = 0.f;
    for (int c = 0; c < NCHUNK; ++c) {
        float cur = bf2f(states[base + (long)c * 4096]);
        states[base + (long)c * 4096] = f2bf(acc);
        acc = __expf(Tp[c]) * acc + cur;
    }
}

// ---- phase C (MFMA): Y = (C.B^T . Lm) @ xd + exp(acs) * (C @ Sprev^T) -> bf16 ybuf ----
__global__ __launch_bounds__(256) void yfull_kernel(const ushort_t* __restrict__ xbc,
                                                    const ushort_t* __restrict__ xT,
                                                    const float* __restrict__ dtbT,
                                                    const float* __restrict__ acs,
                                                    const ushort_t* __restrict__ sprev,
                                                    ushort_t* __restrict__ ybuf) {
    int h = blockIdx.x, c = blockIdx.y, b = blockIdx.z;
    __shared__ __align__(16) ushort_t Cb[64 * PADB];
    __shared__ __align__(16) ushort_t Bb[64 * PADB];
    __shared__ __align__(16) ushort_t Xt[64 * PADB];
    __shared__ __align__(16) ushort_t Sp[64 * PADB];
    __shared__ __align__(16) ushort_t Sm[64 * PADB];
    __shared__ float sAcs[64], sE[64], sDt[64];
    int t = threadIdx.x;
    long rowg0 = (long)b * 4096 + c * 64;
    long acsb = ((long)(b * NH + h) * NCHUNK + c) * 64;
    long spb = ((long)(b * NH + h) * NCHUNK + c) * 4096;
    if (t < 64) {
        float a = acs[acsb + t];
        sAcs[t] = a;
        sE[t] = __expf(a);
        sDt[t] = dtbT[(long)h * BROWS + rowg0 + t];
    }
    __syncthreads();
#pragma unroll
    for (int i = 0; i < 2; ++i) {
        int q = t + 256 * i;
        int l = q >> 3, sg = q & 7;
        const ushort_t* rp = &xbc[(rowg0 + l) * (long)XBCW];
        *(u16x8*)&Cb[l * PADB + sg * 8] = *(const u16x8*)&rp[1600 + sg * 8];
        *(u16x8*)&Bb[l * PADB + sg * 8] = *(const u16x8*)&rp[DINNER + sg * 8];
        u16x8 xv = *(const u16x8*)&xT[(long)(h * 64 + l) * BROWS + rowg0 + sg * 8];
        u16x8 xo;
#pragma unroll
        for (int j = 0; j < 8; ++j) xo[j] = f2bf(bf2f(xv[j]) * sDt[sg * 8 + j]);
        *(u16x8*)&Xt[l * PADB + sg * 8] = xo;
        *(u16x8*)&Sp[l * PADB + sg * 8] = *(const u16x8*)&sprev[spb + l * 64 + sg * 8];
    }
    __syncthreads();
    int w = t >> 6, lane = t & 63;
    int r16 = lane & 15, kg = lane >> 4;
    bfx8 ac[2];
#pragma unroll
    for (int kk = 0; kk < 2; ++kk)
        ac[kk] = *(const bfx8*)&Cb[(w * 16 + r16) * PADB + kk * 32 + kg * 8];
    f32x4 s_acc[4] = {};
#pragma unroll
    for (int j = 0; j < 4; ++j)
#pragma unroll
        for (int kk = 0; kk < 2; ++kk) {
            bfx8 bb = *(const bfx8*)&Bb[(j * 16 + r16) * PADB + kk * 32 + kg * 8];
            s_acc[j] = __builtin_amdgcn_mfma_f32_16x16x32_bf16(ac[kk], bb, s_acc[j], 0, 0, 0);
        }
#pragma unroll
    for (int j = 0; j < 4; ++j)
#pragma unroll
        for (int q = 0; q < 4; ++q) {
            int l = w * 16 + kg * 4 + q;
            int s = j * 16 + r16;
            float v = s_acc[j][q];
            v = (s <= l) ? v * __expf(sAcs[l] - sAcs[s]) : 0.f;
            Sm[l * PADB + s] = f2bf(v);
        }
    __syncthreads();
    bfx8 as[2];
#pragma unroll
    for (int kk = 0; kk < 2; ++kk)
        as[kk] = *(const bfx8*)&Sm[(w * 16 + r16) * PADB + kk * 32 + kg * 8];
    f32x4 d_acc[4] = {}, o_acc[4] = {};
#pragma unroll
    for (int j = 0; j < 4; ++j)
#pragma unroll
        for (int kk = 0; kk < 2; ++kk) {
            bfx8 xb = *(const bfx8*)&Xt[(j * 16 + r16) * PADB + kk * 32 + kg * 8];
            d_acc[j] = __builtin_amdgcn_mfma_f32_16x16x32_bf16(as[kk], xb, d_acc[j], 0, 0, 0);
            bfx8 sb = *(const bfx8*)&Sp[(j * 16 + r16) * PADB + kk * 32 + kg * 8];
            o_acc[j] = __builtin_amdgcn_mfma_f32_16x16x32_bf16(ac[kk], sb, o_acc[j], 0, 0, 0);
        }
#pragma unroll
    for (int j = 0; j < 4; ++j)
#pragma unroll
        for (int q = 0; q < 4; ++q) {
            int l = w * 16 + kg * 4 + q;
            int p = j * 16 + r16;
            Bb[l * PADB + p] = f2bf(d_acc[j][q] + sE[l] * o_acc[j][q]);
        }
    __syncthreads();
#pragma unroll
    for (int i = 0; i < 2; ++i) {
        int q = t + 256 * i;
        int l = q >> 3, sg = q & 7;
        *(u16x8*)&ybuf[(rowg0 + l) * (long)DINNER + h * 64 + sg * 8] =
            *(const u16x8*)&Bb[l * PADB + sg * 8];
    }
}

// ---- gated RMS norm -> bf16 ----
__global__ __launch_bounds__(256) void norm_kernel(const ushort_t* __restrict__ ybuf,
                                                   const ushort_t* __restrict__ xbc,
                                                   const ushort_t* __restrict__ zbf,
                                                   const float* __restrict__ Dp,
                                                   const float* __restrict__ normw,
                                                   ushort_t* __restrict__ ybf) {
    int row = blockIdx.x;
    int t = threadIdx.x;
    float g[6];
    float ss = 0.f;
#pragma unroll
    for (int i = 0; i < 6; ++i) {
        int j = t + 256 * i;
        int h = j >> 6;
        float x = bf2f(xbc[(long)row * XBCW + j]);
        float yy = bf2f(ybuf[(long)row * DINNER + j]) + x * Dp[h];
        float z = bf2f(zbf[(long)row * DINNER + j]);
        float gz = z / (1.f + __expf(-z));
        float v = yy * gz;
        g[i] = v;
        ss += v * v;
    }
#pragma unroll
    for (int o = 32; o > 0; o >>= 1) ss += __shfl_xor(ss, o, 64);
    __shared__ float wsum[4];
    __shared__ float sscale;
    int w = t >> 6;
    if ((t & 63) == 0) wsum[w] = ss;
    __syncthreads();
    if (t == 0) {
        float tot = wsum[0] + wsum[1] + wsum[2] + wsum[3];
        sscale = rsqrtf(tot / (float)DINNER + 1e-5f);
    }
    __syncthreads();
    float sc = sscale;
#pragma unroll
    for (int i = 0; i < 6; ++i) {
        int j = t + 256 * i;
        ybf[(long)row * DINNER + j] = f2bf(g[i] * sc * normw[j]);
    }
}

extern "C" void kernel_launch(void* const* d_in, const int* in_sizes, int n_in,
                              void* d_out, int out_size, void* d_ws, size_t ws_size,
                              hipStream_t stream) {
    const float* u = (const float*)d_in[0];
    const float* W_in = (const float*)d_in[1];
    const float* conv_w = (const float*)d_in[2];
    const float* conv_b = (const float*)d_in[3];
    const float* dt_bias = (const float*)d_in[4];
    const float* A_log = (const float*)d_in[5];
    const float* Dp = (const float*)d_in[6];
    const float* norm_w = (const float*)d_in[7];
    const float* W_out = (const float*)d_in[8];
    float* out = (float*)d_out;

    char* ws = (char*)d_ws;
    size_t off = 0;
    auto alloc = [&](size_t bytes) {
        void* p = ws + off;
        off += (bytes + 255) & ~(size_t)255;
        return p;
    };
    ushort_t* zbf = (ushort_t*)alloc((size_t)BROWS * DINNER * 2);      // 25.2 MB
    ushort_t* xbcrawbf = (ushort_t*)alloc((size_t)BROWS * XBCW * 2);   // 27.3 MB
    ushort_t* xbc = (ushort_t*)alloc((size_t)BROWS * XBCW * 2);        // 27.3 MB
    ushort_t* xT = (ushort_t*)alloc((size_t)1600 * BROWS * 2);         // 26.2 MB
    float* dtbT = (float*)alloc((size_t)NH * BROWS * 4);               // 0.79 MB
    float* acs = (float*)alloc((size_t)2 * NH * NCHUNK * 64 * 4);      // 0.79 MB
    float* Tsum = (float*)alloc((size_t)2 * NH * NCHUNK * 4);          // 12 KB
    ushort_t* states = (ushort_t*)alloc((size_t)2 * NH * NCHUNK * 4096 * 2);  // 25.2 MB
    ushort_t* ybuf = (ushort_t*)alloc((size_t)BROWS * DINNER * 2);     // 25.2 MB
    ushort_t* woutbf = (ushort_t*)alloc((size_t)DM * DINNER * 2);      // 2.4 MB (own slot)
    // aliases with disjoint lifetimes:
    ushort_t* ybf = xbcrawbf;             // xbcrawbf dead after convxt
    ushort_t* ubf = ybuf;                 // u-bf16 dead after gemm1; ybuf written in yfull
    ushort_t* winbf = states;             // W_in-bf16 dead after gemm1; states written after

    if (off > ws_size) {
        fill_kernel<<<(out_size + 255) / 256, 256, 0, stream>>>(out, out_size, 12345.0f);
        return;
    }

    // all input conversions in one launch
    {
        const long NU = (long)BROWS * DM / 4;
        const long NW = (long)NPAD1 * 192;
        const long NO = (long)DM * DINNER / 4;
        long nblk = (NU + NW + NO + 255) / 256;
        cvt_all<<<(int)nblk, 256, 0, stream>>>(u, W_in, W_out, ubf, winbf, woutbf);
    }

    // in-projection, 512-thread M128xN256 tile, 2-buffer (48KB -> 3 blocks/CU)
    gemm1_512<<<dim3(13, 64), 512, 0, stream>>>(ubf, winbf, DM, zbf, xbcrawbf, dtbT, dt_bias);

    // fused conv+silu+transpose
    convxt_kernel<<<dim3(128, 26), 256, 0, stream>>>(xbcrawbf, conv_w, conv_b, xbc, xT);

    acs_kernel<<<2 * NH, 256, 0, stream>>>(dtbT, A_log, acs, Tsum);
    states_kernel<<<dim3(NH, NCHUNK, 2), 256, 0, stream>>>(xT, dtbT, acs, Tsum, states);
    scan_kernel<<<dim3(16, NH, 2), 256, 0, stream>>>(Tsum, states);
    yfull_kernel<<<dim3(NH, NCHUNK, 2), 256, 0, stream>>>(xbc, xT, dtbT, acs, states, ybuf);

    norm_kernel<<<BROWS, 256, 0, stream>>>(ybuf, xbc, zbf, Dp, norm_w, ybf);

    // out-projection, 128x128 tile (384 blocks; best measured for N=768)
    gemm_bt<<<dim3(6, 64), 256, 0, stream>>>(ybf, woutbf, out, DINNER, DM);
}

// Round 24
// 242.015 us; speedup vs baseline: 1.0568x; 1.0107x over previous
//
#include <hip/hip_runtime.h>

typedef __attribute__((ext_vector_type(4))) float f4;
typedef __attribute__((ext_vector_type(8))) short bfx8;
typedef __attribute__((ext_vector_type(4))) float f32x4;
typedef __attribute__((ext_vector_type(4))) unsigned int u32x4;
typedef __attribute__((ext_vector_type(4))) unsigned short u16x4;
typedef __attribute__((ext_vector_type(8))) unsigned short u16x8;
typedef unsigned short ushort_t;

#define DM 768
#define DINNER 1536
#define NH 24
#define XBCW 1664
#define DINPROJ 3224
#define NPAD1 3328
#define NCHUNK 64
#define BROWS 8192
#define PADB 72  // bf16 LDS row stride for 64-wide tiles

__device__ inline ushort_t f2bf(float f) {
    unsigned u = __builtin_bit_cast(unsigned, f);
    unsigned r = (u + 0x7FFF + ((u >> 16) & 1)) >> 16;
    return (ushort_t)r;
}
__device__ inline float bf2f(ushort_t u) {
    return __builtin_bit_cast(float, (unsigned)u << 16);
}
// direct global->LDS 16B staging. dst wave-uniform; HW adds lane*16.
__device__ inline void gl16(const void* g, void* l) {
    __builtin_amdgcn_global_load_lds((const __attribute__((address_space(1))) void*)g,
                                     (__attribute__((address_space(3))) void*)l, 16, 0, 0);
}

__global__ __launch_bounds__(256) void fill_kernel(float* out, int n, float v) {
    int i = blockIdx.x * 256 + threadIdx.x;
    if (i < n) out[i] = v;
}

// ---- all three f32->bf16 input conversions in one launch ----
__global__ __launch_bounds__(256) void cvt_all(const float* __restrict__ u,
                                               const float* __restrict__ W_in,
                                               const float* __restrict__ W_out,
                                               ushort_t* __restrict__ ubf,
                                               ushort_t* __restrict__ winbf,
                                               ushort_t* __restrict__ woutbf) {
    const long NU = (long)BROWS * DM / 4;
    const long NW = (long)NPAD1 * 192;
    const long NO = (long)DM * DINNER / 4;
    long q = (long)blockIdx.x * 256 + threadIdx.x;
    if (q < NU) {
        f4 v = *(const f4*)&u[q * 4];
        u16x4 o;
        o[0] = f2bf(v[0]); o[1] = f2bf(v[1]); o[2] = f2bf(v[2]); o[3] = f2bf(v[3]);
        *(u16x4*)&ubf[q * 4] = o;
    } else if (q < NU + NW) {
        long p = q - NU;
        int row = (int)(p / 192);
        int cq = (int)(p % 192);
        u16x4 o = {0, 0, 0, 0};
        if (row < DINPROJ) {
            f4 v = *(const f4*)&W_in[(long)row * DM + cq * 4];
            o[0] = f2bf(v[0]); o[1] = f2bf(v[1]); o[2] = f2bf(v[2]); o[3] = f2bf(v[3]);
        }
        *(u16x4*)&winbf[p * 4] = o;
    } else if (q < NU + NW + NO) {
        long p = q - NU - NW;
        f4 v = *(const f4*)&W_out[p * 4];
        u16x4 o;
        o[0] = f2bf(v[0]); o[1] = f2bf(v[1]); o[2] = f2bf(v[2]); o[3] = f2bf(v[3]);
        *(u16x4*)&woutbf[p * 4] = o;
    }
}

// ---- in-proj GEMM: 512 threads / 8 waves, tile M128 x N256, BK=32,
//      2-buffer double-buffered gl16 (48KB LDS -> 3 blocks/CU), XCD swizzle.
__global__ __launch_bounds__(512) void gemm1_512(const ushort_t* __restrict__ A,
                                                 const ushort_t* __restrict__ B,
                                                 int K,
                                                 ushort_t* __restrict__ zbf,
                                                 ushort_t* __restrict__ xbcbf,
                                                 float* __restrict__ dtbT,
                                                 const float* __restrict__ dt_bias) {
    __shared__ __align__(16) ushort_t As[2][128 * 32];  // 8KB each
    __shared__ __align__(16) ushort_t Bs[2][256 * 32];  // 16KB each
    int tid = threadIdx.x;
    int lane = tid & 63;
    int w = tid >> 6;          // 0..7
    int wr = w >> 2, wc = w & 3;
    int gx = gridDim.x;        // 13
    int nwg = gx * gridDim.y;  // 832
    int id = blockIdx.y * gx + blockIdx.x;
    int per = nwg >> 3;
    int id2 = (id & 7) * per + (id >> 3);
    int m0 = (id2 / gx) * 128;
    int n0 = (id2 % gx) * 256;
    int r16 = lane & 15, kg = lane >> 4;

    int row0 = tid >> 2, cof0 = (tid & 3) * 8;
    const ushort_t* abase = &A[(long)(m0 + row0) * K + cof0];
    const ushort_t* bb0 = &B[(long)(n0 + row0) * K + cof0];
    const ushort_t* bb1 = &B[(long)(n0 + row0 + 128) * K + cof0];

    f32x4 acc[4][4] = {};
    int nk = K >> 5;

    auto issue = [&](int t, int buf) {
        long k = (long)t << 5;
        char* ab = (char*)&As[buf][0] + w * 1024;
        char* bb = (char*)&Bs[buf][0] + w * 1024;
        gl16(abase + k, ab);
        gl16(bb0 + k, bb);
        gl16(bb1 + k, bb + 8192);
    };
    issue(0, 0);
    asm volatile("s_waitcnt vmcnt(0)" ::: "memory");
    __builtin_amdgcn_s_barrier();

    int cur = 0;
    for (int t = 0; t < nk; ++t) {
        if (t + 1 < nk) issue(t + 1, cur ^ 1);  // loads fly under this tile's compute
        const ushort_t* Asc = &As[cur][0];
        const ushort_t* Bsc = &Bs[cur][0];
        bfx8 af[4], bfr[4];
#pragma unroll
        for (int i = 0; i < 4; ++i)
            af[i] = *(const bfx8*)&Asc[(wr * 64 + i * 16 + r16) * 32 + kg * 8];
#pragma unroll
        for (int j = 0; j < 4; ++j)
            bfr[j] = *(const bfx8*)&Bsc[(wc * 64 + j * 16 + r16) * 32 + kg * 8];
#pragma unroll
        for (int i = 0; i < 4; ++i)
#pragma unroll
            for (int j = 0; j < 4; ++j)
                acc[i][j] = __builtin_amdgcn_mfma_f32_16x16x32_bf16(af[i], bfr[j], acc[i][j], 0, 0, 0);
        asm volatile("s_waitcnt vmcnt(0)" ::: "memory");  // prefetch landed
        __builtin_amdgcn_s_barrier();                      // all reads of cur done
        cur ^= 1;
    }

#pragma unroll
    for (int i = 0; i < 4; ++i) {
        int rowb = m0 + wr * 64 + i * 16 + kg * 4;
#pragma unroll
        for (int j = 0; j < 4; ++j) {
            int col = n0 + wc * 64 + j * 16 + r16;
            if (col < DINNER) {  // z -> bf16
#pragma unroll
                for (int q = 0; q < 4; ++q)
                    zbf[(long)(rowb + q) * DINNER + col] = f2bf(acc[i][j][q]);
            } else if (col < 3200) {  // xBC -> bf16
#pragma unroll
                for (int q = 0; q < 4; ++q)
                    xbcbf[(long)(rowb + q) * XBCW + col - DINNER] = f2bf(acc[i][j][q]);
            } else if (col < DINPROJ) {  // dt -> softplus -> transposed
                int h = col - 3200;
                float bias = dt_bias[h];
#pragma unroll
                for (int q = 0; q < 4; ++q) {
                    float v = acc[i][j][q] + bias;
                    float d = (v > 20.f) ? v : log1pf(__expf(v));
                    dtbT[(long)h * BROWS + rowb + q] = d;
                }
            }
        }
    }
}

// ---- out-proj GEMM C[M][ldc](f32) = A * B^T, 128x128, BK=32,
//      2-buffer double-buffered gl16 (32KB LDS -> 5 blocks/CU), XCD swizzle ----
__global__ __launch_bounds__(256) void gemm_bt(const ushort_t* __restrict__ A,
                                               const ushort_t* __restrict__ B,
                                               float* __restrict__ C,
                                               int K, int ldc) {
    __shared__ __align__(16) ushort_t As[2][128 * 32];
    __shared__ __align__(16) ushort_t Bs[2][128 * 32];
    int tid = threadIdx.x;
    int lane = tid & 63;
    int w = tid >> 6;
    int wr = w >> 1, wc = w & 1;
    int gx = gridDim.x;
    int nwg = gx * gridDim.y;
    int id = blockIdx.y * gx + blockIdx.x;
    int per = nwg >> 3;
    int id2 = (id & 7) * per + (id >> 3);
    int m0 = (id2 / gx) * 128;
    int n0 = (id2 % gx) * 128;
    int r16 = lane & 15, kg = lane >> 4;

    int row0 = tid >> 2, cof0 = (tid & 3) * 8;
    const ushort_t* a0 = &A[(long)(m0 + row0) * K + cof0];
    const ushort_t* a1 = &A[(long)(m0 + row0 + 64) * K + cof0];
    const ushort_t* b0 = &B[(long)(n0 + row0) * K + cof0];
    const ushort_t* b1 = &B[(long)(n0 + row0 + 64) * K + cof0];

    f32x4 acc[4][4] = {};
    int nk = K >> 5;

    auto issue = [&](int t, int buf) {
        int k = t << 5;
        char* ab = (char*)&As[buf][0] + w * 1024;
        char* bb = (char*)&Bs[buf][0] + w * 1024;
        gl16(a0 + k, ab); gl16(a1 + k, ab + 4096);
        gl16(b0 + k, bb); gl16(b1 + k, bb + 4096);
    };
    issue(0, 0);
    asm volatile("s_waitcnt vmcnt(0)" ::: "memory");
    __builtin_amdgcn_s_barrier();

    int cur = 0;
    for (int t = 0; t < nk; ++t) {
        if (t + 1 < nk) issue(t + 1, cur ^ 1);
        const ushort_t* Asc = &As[cur][0];
        const ushort_t* Bsc = &Bs[cur][0];
        bfx8 af[4], bfr[4];
#pragma unroll
        for (int i = 0; i < 4; ++i) {
            af[i] = *(const bfx8*)&Asc[(wr * 64 + i * 16 + r16) * 32 + kg * 8];
            bfr[i] = *(const bfx8*)&Bsc[(wc * 64 + i * 16 + r16) * 32 + kg * 8];
        }
#pragma unroll
        for (int i = 0; i < 4; ++i)
#pragma unroll
            for (int j = 0; j < 4; ++j)
                acc[i][j] = __builtin_amdgcn_mfma_f32_16x16x32_bf16(af[i], bfr[j], acc[i][j], 0, 0, 0);
        asm volatile("s_waitcnt vmcnt(0)" ::: "memory");
        __builtin_amdgcn_s_barrier();
        cur ^= 1;
    }

#pragma unroll
    for (int i = 0; i < 4; ++i) {
        int rowb = m0 + wr * 64 + i * 16 + kg * 4;
#pragma unroll
        for (int j = 0; j < 4; ++j) {
            int col = n0 + wc * 64 + j * 16 + r16;
#pragma unroll
            for (int q = 0; q < 4; ++q)
                C[(long)(rowb + q) * ldc + col] = acc[i][j][q];
        }
    }
}

// ---- fused conv(4)+silu + transpose: reads xbcrawbf, writes xbc AND xT (ch<1600) ----
__global__ __launch_bounds__(256) void convxt_kernel(const ushort_t* __restrict__ xin,
                                                     const float* __restrict__ cw,
                                                     const float* __restrict__ cb,
                                                     ushort_t* __restrict__ xbc,
                                                     ushort_t* __restrict__ xT) {
    __shared__ ushort_t tile[64][PADB];
    int rt = blockIdx.x;  // 128 row-tiles
    int ct = blockIdx.y;  // 26 ch-tiles
    int t = threadIdx.x;
#pragma unroll
    for (int i = 0; i < 2; ++i) {
        int q = t + 256 * i;
        int r = q >> 3, c8 = q & 7;
        int row = rt * 64 + r;
        int b = row >> 12, l = row & 4095;
        int ch = ct * 64 + c8 * 8;
        float a[8];
#pragma unroll
        for (int j = 0; j < 8; ++j) a[j] = cb[ch + j];
#pragma unroll
        for (int k = 0; k < 4; ++k) {
            int ll = l - 3 + k;
            if (ll >= 0) {
                u16x8 v = *(const u16x8*)&xin[(long)(b * 4096 + ll) * XBCW + ch];
#pragma unroll
                for (int j = 0; j < 8; ++j) a[j] += cw[(ch + j) * 4 + k] * bf2f(v[j]);
            }
        }
        u16x8 o;
#pragma unroll
        for (int j = 0; j < 8; ++j) {
            float s = a[j] / (1.f + __expf(-a[j]));
            o[j] = f2bf(s);
        }
        *(u16x8*)&xbc[(long)row * XBCW + ch] = o;
        *(u16x8*)&tile[r][c8 * 8] = o;
    }
    __syncthreads();
    if (ct < 25) {
#pragma unroll
        for (int i = 0; i < 2; ++i) {
            int q = t + 256 * i;
            int ch = q >> 3, sg = q & 7;
            u16x8 o;
#pragma unroll
            for (int k = 0; k < 8; ++k) o[k] = tile[sg * 8 + k][ch];
            *(u16x8*)&xT[(long)(ct * 64 + ch) * BROWS + rt * 64 + sg * 8] = o;
        }
    }
}

// ---- per-chunk cumsum of A*dt via wave scan ----
__global__ __launch_bounds__(256) void acs_kernel(const float* __restrict__ dtbT,
                                                  const float* __restrict__ A_log,
                                                  float* __restrict__ acs,
                                                  float* __restrict__ Tsum) {
    int bh = blockIdx.x;
    int b = bh / NH, h = bh % NH;
    int t = threadIdx.x;
    int lane = t & 63;
    float A = -__expf(A_log[h]);
    const float* dp = &dtbT[(long)h * BROWS + b * 4096];
#pragma unroll
    for (int it = 0; it < 16; ++it) {
        int c = (t >> 6) + 4 * it;
        float v = A * dp[c * 64 + lane];
#pragma unroll
        for (int off = 1; off < 64; off <<= 1) {
            float u = __shfl_up(v, off, 64);
            if (lane >= off) v += u;
        }
        acs[((long)bh * NCHUNK + c) * 64 + lane] = v;
        if (lane == 63) Tsum[bh * NCHUNK + c] = v;
    }
}

// ---- phase A (MFMA): states[p][n] = sum_l (x*dt*decay)[l][p] * B[l][n] -> bf16 ----
__global__ __launch_bounds__(256) void states_kernel(const ushort_t* __restrict__ xT,
                                                     const float* __restrict__ dtbT,
                                                     const float* __restrict__ acs,
                                                     const float* __restrict__ Tsum,
                                                     ushort_t* __restrict__ states) {
    int h = blockIdx.x, c = blockIdx.y, b = blockIdx.z;
    __shared__ __align__(16) ushort_t Wt[64 * PADB];
    __shared__ __align__(16) ushort_t Bt[64 * PADB];
    __shared__ float sDec[64];
    int t = threadIdx.x;
    long rowg0 = (long)b * 4096 + c * 64;
    long acsb = ((long)(b * NH + h) * NCHUNK + c) * 64;
    float T = Tsum[(b * NH + h) * NCHUNK + c];
    if (t < 64)
        sDec[t] = dtbT[(long)h * BROWS + rowg0 + t] * __expf(T - acs[acsb + t]);
    __syncthreads();
#pragma unroll
    for (int i = 0; i < 2; ++i) {
        int q = t + 256 * i;
        int p = q >> 3, sg = q & 7;
        u16x8 xv = *(const u16x8*)&xT[(long)(h * 64 + p) * BROWS + rowg0 + sg * 8];
        u16x8 wv;
#pragma unroll
        for (int j = 0; j < 8; ++j) wv[j] = f2bf(bf2f(xv[j]) * sDec[sg * 8 + j]);
        *(u16x8*)&Wt[p * PADB + sg * 8] = wv;
        *(u16x8*)&Bt[p * PADB + sg * 8] =
            *(const u16x8*)&xT[(long)(DINNER + p) * BROWS + rowg0 + sg * 8];
    }
    __syncthreads();
    int w = t >> 6, lane = t & 63;
    int r16 = lane & 15, kg = lane >> 4;
    bfx8 aw[2];
#pragma unroll
    for (int kk = 0; kk < 2; ++kk)
        aw[kk] = *(const bfx8*)&Wt[(w * 16 + r16) * PADB + kk * 32 + kg * 8];
    f32x4 acc[4] = {};
#pragma unroll
    for (int j = 0; j < 4; ++j)
#pragma unroll
        for (int kk = 0; kk < 2; ++kk) {
            bfx8 bb = *(const bfx8*)&Bt[(j * 16 + r16) * PADB + kk * 32 + kg * 8];
            acc[j] = __builtin_amdgcn_mfma_f32_16x16x32_bf16(aw[kk], bb, acc[j], 0, 0, 0);
        }
    __syncthreads();
#pragma unroll
    for (int j = 0; j < 4; ++j)
#pragma unroll
        for (int q = 0; q < 4; ++q)
            Wt[(w * 16 + kg * 4 + q) * PADB + j * 16 + r16] = f2bf(acc[j][q]);
    __syncthreads();
    long ob = ((long)(b * NH + h) * NCHUNK + c) * 4096;
#pragma unroll
    for (int i = 0; i < 2; ++i) {
        int q = t + 256 * i;
        int p = q >> 3, sg = q & 7;
        *(u16x8*)&states[ob + p * 64 + sg * 8] = *(const u16x8*)&Wt[p * PADB + sg * 8];
    }
}

// ---- sequential chunk scan ----
__global__ __launch_bounds__(256) void scan_kernel(const float* __restrict__ Tsum,
                                                   ushort_t* __restrict__ states) {
    int e = blockIdx.x * 256 + threadIdx.x;
    int h = blockIdx.y, b = blockIdx.z;
    long base = ((long)(b * NH + h)) * NCHUNK * 4096 + e;
    const float* Tp = &Tsum[(b * NH + h) * NCHUNK];
    float acc = 0.f;
    for (int c = 0; c < NCHUNK; ++c) {
        float cur = bf2f(states[base + (long)c * 4096]);
        states[base + (long)c * 4096] = f2bf(acc);
        acc = __expf(Tp[c]) * acc + cur;
    }
}

// ---- phase C (MFMA): Y = (C.B^T . Lm) @ xd + exp(acs) * (C @ Sprev^T) -> bf16 ybuf ----
__global__ __launch_bounds__(256) void yfull_kernel(const ushort_t* __restrict__ xbc,
                                                    const ushort_t* __restrict__ xT,
                                                    const float* __restrict__ dtbT,
                                                    const float* __restrict__ acs,
                                                    const ushort_t* __restrict__ sprev,
                                                    ushort_t* __restrict__ ybuf) {
    int h = blockIdx.x, c = blockIdx.y, b = blockIdx.z;
    __shared__ __align__(16) ushort_t Cb[64 * PADB];
    __shared__ __align__(16) ushort_t Bb[64 * PADB];
    __shared__ __align__(16) ushort_t Xt[64 * PADB];
    __shared__ __align__(16) ushort_t Sp[64 * PADB];
    __shared__ __align__(16) ushort_t Sm[64 * PADB];
    __shared__ float sAcs[64], sE[64], sDt[64];
    int t = threadIdx.x;
    long rowg0 = (long)b * 4096 + c * 64;
    long acsb = ((long)(b * NH + h) * NCHUNK + c) * 64;
    long spb = ((long)(b * NH + h) * NCHUNK + c) * 4096;
    if (t < 64) {
        float a = acs[acsb + t];
        sAcs[t] = a;
        sE[t] = __expf(a);
        sDt[t] = dtbT[(long)h * BROWS + rowg0 + t];
    }
    __syncthreads();
#pragma unroll
    for (int i = 0; i < 2; ++i) {
        int q = t + 256 * i;
        int l = q >> 3, sg = q & 7;
        const ushort_t* rp = &xbc[(rowg0 + l) * (long)XBCW];
        *(u16x8*)&Cb[l * PADB + sg * 8] = *(const u16x8*)&rp[1600 + sg * 8];
        *(u16x8*)&Bb[l * PADB + sg * 8] = *(const u16x8*)&rp[DINNER + sg * 8];
        u16x8 xv = *(const u16x8*)&xT[(long)(h * 64 + l) * BROWS + rowg0 + sg * 8];
        u16x8 xo;
#pragma unroll
        for (int j = 0; j < 8; ++j) xo[j] = f2bf(bf2f(xv[j]) * sDt[sg * 8 + j]);
        *(u16x8*)&Xt[l * PADB + sg * 8] = xo;
        *(u16x8*)&Sp[l * PADB + sg * 8] = *(const u16x8*)&sprev[spb + l * 64 + sg * 8];
    }
    __syncthreads();
    int w = t >> 6, lane = t & 63;
    int r16 = lane & 15, kg = lane >> 4;
    bfx8 ac[2];
#pragma unroll
    for (int kk = 0; kk < 2; ++kk)
        ac[kk] = *(const bfx8*)&Cb[(w * 16 + r16) * PADB + kk * 32 + kg * 8];
    f32x4 s_acc[4] = {};
#pragma unroll
    for (int j = 0; j < 4; ++j)
#pragma unroll
        for (int kk = 0; kk < 2; ++kk) {
            bfx8 bb = *(const bfx8*)&Bb[(j * 16 + r16) * PADB + kk * 32 + kg * 8];
            s_acc[j] = __builtin_amdgcn_mfma_f32_16x16x32_bf16(ac[kk], bb, s_acc[j], 0, 0, 0);
        }
#pragma unroll
    for (int j = 0; j < 4; ++j)
#pragma unroll
        for (int q = 0; q < 4; ++q) {
            int l = w * 16 + kg * 4 + q;
            int s = j * 16 + r16;
            float v = s_acc[j][q];
            v = (s <= l) ? v * __expf(sAcs[l] - sAcs[s]) : 0.f;
            Sm[l * PADB + s] = f2bf(v);
        }
    __syncthreads();
    bfx8 as[2];
#pragma unroll
    for (int kk = 0; kk < 2; ++kk)
        as[kk] = *(const bfx8*)&Sm[(w * 16 + r16) * PADB + kk * 32 + kg * 8];
    f32x4 d_acc[4] = {}, o_acc[4] = {};
#pragma unroll
    for (int j = 0; j < 4; ++j)
#pragma unroll
        for (int kk = 0; kk < 2; ++kk) {
            bfx8 xb = *(const bfx8*)&Xt[(j * 16 + r16) * PADB + kk * 32 + kg * 8];
            d_acc[j] = __builtin_amdgcn_mfma_f32_16x16x32_bf16(as[kk], xb, d_acc[j], 0, 0, 0);
            bfx8 sb = *(const bfx8*)&Sp[(j * 16 + r16) * PADB + kk * 32 + kg * 8];
            o_acc[j] = __builtin_amdgcn_mfma_f32_16x16x32_bf16(ac[kk], sb, o_acc[j], 0, 0, 0);
        }
#pragma unroll
    for (int j = 0; j < 4; ++j)
#pragma unroll
        for (int q = 0; q < 4; ++q) {
            int l = w * 16 + kg * 4 + q;
            int p = j * 16 + r16;
            Bb[l * PADB + p] = f2bf(d_acc[j][q] + sE[l] * o_acc[j][q]);
        }
    __syncthreads();
#pragma unroll
    for (int i = 0; i < 2; ++i) {
        int q = t + 256 * i;
        int l = q >> 3, sg = q & 7;
        *(u16x8*)&ybuf[(rowg0 + l) * (long)DINNER + h * 64 + sg * 8] =
            *(const u16x8*)&Bb[l * PADB + sg * 8];
    }
}

// ---- gated RMS norm -> bf16 ----
__global__ __launch_bounds__(256) void norm_kernel(const ushort_t* __restrict__ ybuf,
                                                   const ushort_t* __restrict__ xbc,
                                                   const ushort_t* __restrict__ zbf,
                                                   const float* __restrict__ Dp,
                                                   const float* __restrict__ normw,
                                                   ushort_t* __restrict__ ybf) {
    int row = blockIdx.x;
    int t = threadIdx.x;
    float g[6];
    float ss = 0.f;
#pragma unroll
    for (int i = 0; i < 6; ++i) {
        int j = t + 256 * i;
        int h = j >> 6;
        float x = bf2f(xbc[(long)row * XBCW + j]);
        float yy = bf2f(ybuf[(long)row * DINNER + j]) + x * Dp[h];
        float z = bf2f(zbf[(long)row * DINNER + j]);
        float gz = z / (1.f + __expf(-z));
        float v = yy * gz;
        g[i] = v;
        ss += v * v;
    }
#pragma unroll
    for (int o = 32; o > 0; o >>= 1) ss += __shfl_xor(ss, o, 64);
    __shared__ float wsum[4];
    __shared__ float sscale;
    int w = t >> 6;
    if ((t & 63) == 0) wsum[w] = ss;
    __syncthreads();
    if (t == 0) {
        float tot = wsum[0] + wsum[1] + wsum[2] + wsum[3];
        sscale = rsqrtf(tot / (float)DINNER + 1e-5f);
    }
    __syncthreads();
    float sc = sscale;
#pragma unroll
    for (int i = 0; i < 6; ++i) {
        int j = t + 256 * i;
        ybf[(long)row * DINNER + j] = f2bf(g[i] * sc * normw[j]);
    }
}

extern "C" void kernel_launch(void* const* d_in, const int* in_sizes, int n_in,
                              void* d_out, int out_size, void* d_ws, size_t ws_size,
                              hipStream_t stream) {
    const float* u = (const float*)d_in[0];
    const float* W_in = (const float*)d_in[1];
    const float* conv_w = (const float*)d_in[2];
    const float* conv_b = (const float*)d_in[3];
    const float* dt_bias = (const float*)d_in[4];
    const float* A_log = (const float*)d_in[5];
    const float* Dp = (const float*)d_in[6];
    const float* norm_w = (const float*)d_in[7];
    const float* W_out = (const float*)d_in[8];
    float* out = (float*)d_out;

    char* ws = (char*)d_ws;
    size_t off = 0;
    auto alloc = [&](size_t bytes) {
        void* p = ws + off;
        off += (bytes + 255) & ~(size_t)255;
        return p;
    };
    ushort_t* zbf = (ushort_t*)alloc((size_t)BROWS * DINNER * 2);      // 25.2 MB
    ushort_t* xbcrawbf = (ushort_t*)alloc((size_t)BROWS * XBCW * 2);   // 27.3 MB
    ushort_t* xbc = (ushort_t*)alloc((size_t)BROWS * XBCW * 2);        // 27.3 MB
    ushort_t* xT = (ushort_t*)alloc((size_t)1600 * BROWS * 2);         // 26.2 MB
    float* dtbT = (float*)alloc((size_t)NH * BROWS * 4);               // 0.79 MB
    float* acs = (float*)alloc((size_t)2 * NH * NCHUNK * 64 * 4);      // 0.79 MB
    float* Tsum = (float*)alloc((size_t)2 * NH * NCHUNK * 4);          // 12 KB
    ushort_t* states = (ushort_t*)alloc((size_t)2 * NH * NCHUNK * 4096 * 2);  // 25.2 MB
    ushort_t* ybuf = (ushort_t*)alloc((size_t)BROWS * DINNER * 2);     // 25.2 MB
    ushort_t* woutbf = (ushort_t*)alloc((size_t)DM * DINNER * 2);      // 2.4 MB (own slot)
    // aliases with disjoint lifetimes:
    ushort_t* ybf = xbcrawbf;             // xbcrawbf dead after convxt
    ushort_t* ubf = ybuf;                 // u-bf16 dead after gemm1; ybuf written in yfull
    ushort_t* winbf = states;             // W_in-bf16 dead after gemm1; states written after

    if (off > ws_size) {
        fill_kernel<<<(out_size + 255) / 256, 256, 0, stream>>>(out, out_size, 12345.0f);
        return;
    }

    // all input conversions in one launch
    {
        const long NU = (long)BROWS * DM / 4;
        const long NW = (long)NPAD1 * 192;
        const long NO = (long)DM * DINNER / 4;
        long nblk = (NU + NW + NO + 255) / 256;
        cvt_all<<<(int)nblk, 256, 0, stream>>>(u, W_in, W_out, ubf, winbf, woutbf);
    }

    // in-projection, 512-thread M128xN256 tile, 2-buffer (48KB -> 3 blocks/CU)
    gemm1_512<<<dim3(13, 64), 512, 0, stream>>>(ubf, winbf, DM, zbf, xbcrawbf, dtbT, dt_bias);

    // fused conv+silu+transpose
    convxt_kernel<<<dim3(128, 26), 256, 0, stream>>>(xbcrawbf, conv_w, conv_b, xbc, xT);

    acs_kernel<<<2 * NH, 256, 0, stream>>>(dtbT, A_log, acs, Tsum);
    states_kernel<<<dim3(NH, NCHUNK, 2), 256, 0, stream>>>(xT, dtbT, acs, Tsum, states);
    scan_kernel<<<dim3(16, NH, 2), 256, 0, stream>>>(Tsum, states);
    yfull_kernel<<<dim3(NH, NCHUNK, 2), 256, 0, stream>>>(xbc, xT, dtbT, acs, states, ybuf);

    norm_kernel<<<BROWS, 256, 0, stream>>>(ybuf, xbc, zbf, Dp, norm_w, ybf);

    // out-projection, 128x128 tile, 2-buffer (32KB -> 5 blocks/CU)
    gemm_bt<<<dim3(6, 64), 256, 0, stream>>>(ybf, woutbf, out, DINNER, DM);
}